// Round 12
// baseline (3643.254 us; speedup 1.0000x reference)
//
#include <hip/hip_runtime.h>
#include <hip/hip_bf16.h>

// GumbelSoftmaxTokenizer: B=8, P=16384, FEAT=6, TOK=768, MT=128, K=16, IH=256
// All inputs float32; output buffer float32 (tokens, cents, masks concat).
#define NPT   131072      // B*P
#define BATCH 8
#define PPE   16384
#define MT    128
#define KNN   16
#define TOKD  768
#define ZSPLIT 2          // K-split factor for the IH=256 GEMMs

typedef short bf16x8 __attribute__((ext_vector_type(8)));
typedef float f32x4  __attribute__((ext_vector_type(4)));

#define GL16(g, l) __builtin_amdgcn_global_load_lds(                         \
    (const __attribute__((address_space(1))) void*)(g),                      \
    (__attribute__((address_space(3))) void*)(l), 16, 0, 0)

__device__ __forceinline__ unsigned pack_hi(unsigned u0, unsigned u1) {
    return (u0 >> 16) | (u1 & 0xFFFF0000u);
}
__device__ __forceinline__ void split1(float x, short& h, short& l) {
    const unsigned u = __float_as_uint(x);
    h = (short)(u >> 16);
    const float r = x - __uint_as_float(u & 0xFFFF0000u);
    l = (short)(__float_as_uint(r) >> 16);
}

// ---------------------------------------------------------------------------
// prep: c4f[i] = coords[i,1:5] packed float4
// ---------------------------------------------------------------------------
__global__ __launch_bounds__(256) void prep_kernel(const float* __restrict__ coords,
                                                   float4* __restrict__ c4f)
{
    const int i = blockIdx.x * 256 + threadIdx.x;
    if (i < NPT) {
        const long b = (long)i * 5;
        c4f[i] = make_float4(coords[b + 1], coords[b + 2], coords[b + 3], coords[b + 4]);
    }
}

// ---------------------------------------------------------------------------
// All weight pre-converts in ONE launch (segments by blockIdx)
// ---------------------------------------------------------------------------
__global__ __launch_bounds__(256) void wsplit_all(
    const float* __restrict__ w2, const float* __restrict__ w3,
    const float* __restrict__ w4, const float* __restrict__ iw2,
    const float* __restrict__ nw1, const float* __restrict__ nw2,
    short* w2h, short* w2l, short* w3h, short* w3l,
    short* w4h, short* w4l, short* i2h, short* i2l,
    short* n1h, short* n1l, short* n2h, short* n2l)
{
    const int b = blockIdx.x;
    const float* W; int K, N, Kpad, n; short *hi, *lo;
    if (b < 512)       { W = w2;  K = 256; N = 512; Kpad = 256; hi = w2h; lo = w2l; n = b; }
    else if (b < 1280) { W = w3;  K = 512; N = 768; Kpad = 512; hi = w3h; lo = w3l; n = b - 512; }
    else if (b < 2048) { W = w4;  K = 768; N = 768; Kpad = 768; hi = w4h; lo = w4l; n = b - 1280; }
    else if (b < 2304) { W = iw2; K = 256; N = 256; Kpad = 256; hi = i2h; lo = i2l; n = b - 2048; }
    else if (b < 3072) { W = nw1; K = 768; N = 768; Kpad = 768; hi = n1h; lo = n1l; n = b - 2304; }
    else               { W = nw2; K = 768; N = 768; Kpad = 768; hi = n2h; lo = n2l; n = b - 3072; }
    for (int k = threadIdx.x; k < Kpad; k += 256) {
        short h = 0, l = 0;
        if (k < K) split1(W[(long)k * N + n], h, l);
        hi[(long)n * Kpad + k] = h;
        lo[(long)n * Kpad + k] = l;
    }
}

// ---------------------------------------------------------------------------
// W45 fusion, parallel form: 801 blocks.
// ---------------------------------------------------------------------------
__global__ __launch_bounds__(256) void w45_kernel(const float* __restrict__ w4,
                                                  const float* __restrict__ iw1,
                                                  const float* __restrict__ b4,
                                                  const float* __restrict__ ib1,
                                                  short* __restrict__ hi,
                                                  short* __restrict__ lo,
                                                  float* __restrict__ bias45)
{
    const int k = blockIdx.x, n = threadIdx.x;
    if (k < 768) {
        const float* wr = w4 + (long)k * 768;
        float v0 = 0.f, v1 = 0.f, v2 = 0.f, v3 = 0.f;
        for (int j = 0; j < 768; j += 4) {
            v0 += wr[j]     * iw1[(long)j * 256 + n];
            v1 += wr[j + 1] * iw1[(long)(j + 1) * 256 + n];
            v2 += wr[j + 2] * iw1[(long)(j + 2) * 256 + n];
            v3 += wr[j + 3] * iw1[(long)(j + 3) * 256 + n];
        }
        const float v = (v0 + v1) + (v2 + v3);
        short h, l; split1(v, h, l);
        hi[(long)n * 800 + k] = h;
        lo[(long)n * 800 + k] = l;
    } else if (k < 800) {
        const float v = (k < 772) ? iw1[(long)k * 256 + n] : 0.f;
        short h, l; split1(v, h, l);
        hi[(long)n * 800 + k] = h;
        lo[(long)n * 800 + k] = l;
    } else {
        float v0 = 0.f, v1 = 0.f, v2 = 0.f, v3 = 0.f;
        for (int j = 0; j < 768; j += 4) {
            v0 += b4[j]     * iw1[(long)j * 256 + n];
            v1 += b4[j + 1] * iw1[(long)(j + 1) * 256 + n];
            v2 += b4[j + 2] * iw1[(long)(j + 2) * 256 + n];
            v3 += b4[j + 3] * iw1[(long)(j + 3) * 256 + n];
        }
        bias45[n] = (v0 + v1) + (v2 + v3) + ib1[n];
    }
}

// ---------------------------------------------------------------------------
// L1 multi-row: 64 rows/block
// ---------------------------------------------------------------------------
__global__ __launch_bounds__(256) void l1_kernel(const float* __restrict__ f,
                                                 const float* __restrict__ w1,
                                                 const float* __restrict__ b1,
                                                 short* __restrict__ hp,
                                                 short* __restrict__ lp,
                                                 int base,
                                                 const int* __restrict__ gather)
{
    const int r0 = blockIdx.x << 6, tid = threadIdx.x;
    float wc[6];
#pragma unroll
    for (int k = 0; k < 6; ++k) wc[k] = w1[k * 256 + tid];
    const float bb = b1[tid];
    for (int i = 0; i < 64; ++i) {
        const int r = r0 + i;
        int row = gather ? gather[r] : (base + r);
        row = (row < 0) ? 0 : ((row >= NPT) ? (NPT - 1) : row);
        float acc = bb;
#pragma unroll
        for (int k = 0; k < 6; ++k) acc += f[(long)row * 6 + k] * wc[k];
        acc = fmaxf(acc, 0.f);
        short h, l; split1(acc, h, l);
        hp[(long)r * 256 + tid] = h;
        lp[(long)r * 256 + tid] = l;
    }
}

// ---------------------------------------------------------------------------
// gather_h3: G[i][0:768] = H3[knn[off+i]][0:768]
// ---------------------------------------------------------------------------
__global__ __launch_bounds__(256) void gather_h3_kernel(const short* __restrict__ H3,
                                                        const int* __restrict__ knn_idx,
                                                        int off,
                                                        short* __restrict__ G)
{
    const int i = blockIdx.x;
    const int row = knn_idx[off + i];
    const int4* src = (const int4*)(H3 + (long)row * 768);
    int4* dst = (int4*)(G + (long)i * 768);
    if (threadIdx.x < 96) dst[threadIdx.x] = src[threadIdx.x];
}

// ---------------------------------------------------------------------------
// Split-bf16 MFMA GEMM, 128x128 tile, 4 waves in 2x2 (wave = 64x64 sub-tile).
// K-SPLIT (non-atomic): Z = gridDim.z; block z computes K-steps
// [nk*z/Z, nk*(z+1)/Z) and stores RAW fp32 partials (no bias/relu) to
// Cf + z*partStride with plain coalesced stores. Consumer sums the Z slabs.
// Phase order per K-step (T3-minimum): ds_read frags -> barrier ->
// stage(t+1) -> MFMA -> barrier (drain hides under compute).
// LDS XOR-swizzled (0 bank conflicts, verified r1-r2).
// launch_bounds(256,3): VERIFIED config (84 VGPR, no spill). (256,5) forces
// the 8-wave VGPR step (<=64) -> 48 VGPR -> acc[] spills to scratch
// (FETCH 590MB/WRITE 939MB per dispatch, 4x regression — round 10).
// Occupancy steps are 8/4/2 waves at VGPR <=64/128/256; 84 VGPR already
// sits on the 4-wave step.
// Optional fused 16-row-group max-pool (Cpool) and fused coord-fill (CoordC).
// ---------------------------------------------------------------------------
__global__ __launch_bounds__(256, 3) void gemm_mf(
    const short* __restrict__ Aph, const short* __restrict__ Apl,
    const float* __restrict__ Afp, int Kpad,
    const short* __restrict__ Wth, const short* __restrict__ Wtl,
    const float* __restrict__ bias,
    short* __restrict__ Cph, short* __restrict__ Cpl, int KpadOut,
    float* __restrict__ Cf, short* __restrict__ Cp768,
    float* __restrict__ Cpool,
    const float* __restrict__ CoordC, int cfBase,
    int N, int relu, long partStride)
{
    __shared__ short Ah[128 * 32];
    __shared__ short Al[128 * 32];
    __shared__ short Bh[128 * 32];
    __shared__ short Bl[128 * 32];
    const int tid = threadIdx.x;
    int rowb, colb;
    {
        const int ncol = gridDim.x, nrow = gridDim.y;
        if ((nrow & 7) == 0) {
            const int id  = blockIdx.y * ncol + blockIdx.x;
            const int sgs = ncol << 3;
            const int sg = id / sgs, wi = id % sgs;
            rowb = (sg << 3) + (wi & 7);
            colb = wi >> 3;
        } else { rowb = blockIdx.y; colb = blockIdx.x; }
    }
    const int row0 = rowb << 7, col0 = colb << 7;
    const int wave = tid >> 6, lane = tid & 63;
    const int wr = wave >> 1, wc = wave & 1;
    const int q = lane >> 4, l16 = lane & 15;
    const int l2 = lane >> 2;
    // staging source chunk (pre-swizzled so linear LDS dest ends up swizzled)
    const int ksw = (((lane & 3) ^ ((lane >> 3) & 3)) << 3);
    // read-side xor (row mod 16 via l16)
    const int rchunk = ((q ^ ((l16 >> 1) & 3)) << 3);

    f32x4 acc[4][4];
#pragma unroll
    for (int mt = 0; mt < 4; ++mt)
#pragma unroll
        for (int nt = 0; nt < 4; ++nt)
            acc[mt][nt] = (f32x4){0.f, 0.f, 0.f, 0.f};

    const bool useAl = (Apl != nullptr) || (Aph == nullptr);
    const int nkT = Kpad >> 5;
    const int Z = gridDim.z, zb = blockIdx.z;
    const int t0 = (nkT * zb) / Z, t1 = (nkT * (zb + 1)) / Z;

    auto stage = [&](int t) {
        const int k0 = t << 5;
#pragma unroll
        for (int i = 0; i < 2; ++i) {
            const int mb = (wave << 5) + (i << 4);
            const long gb = (long)(col0 + mb + l2) * Kpad + k0 + ksw;
            GL16(&Wth[gb], &Bh[mb * 32]);
            GL16(&Wtl[gb], &Bl[mb * 32]);
        }
        if (Aph) {
#pragma unroll
            for (int i = 0; i < 2; ++i) {
                const int mb = (wave << 5) + (i << 4);
                const long ga = (long)(row0 + mb + l2) * Kpad + k0 + ksw;
                GL16(&Aph[ga], &Ah[mb * 32]);
                if (Apl) GL16(&Apl[ga], &Al[mb * 32]);
            }
        } else {
#pragma unroll
            for (int s = 0; s < 4; ++s) {
                const int l  = (s << 8) + tid;
                const int m  = l >> 3;
                const int k4 = (l & 7) << 2;
                const float4 v = *(const float4*)&Afp[(long)(row0 + m) * Kpad + k0 + k4];
                const unsigned u0 = __float_as_uint(v.x), u1 = __float_as_uint(v.y);
                const unsigned u2 = __float_as_uint(v.z), u3 = __float_as_uint(v.w);
                const unsigned r0 = __float_as_uint(v.x - __uint_as_float(u0 & 0xFFFF0000u));
                const unsigned r1 = __float_as_uint(v.y - __uint_as_float(u1 & 0xFFFF0000u));
                const unsigned r2 = __float_as_uint(v.z - __uint_as_float(u2 & 0xFFFF0000u));
                const unsigned r3 = __float_as_uint(v.w - __uint_as_float(u3 & 0xFFFF0000u));
                const int off = m * 32 + ((((k4 >> 3) ^ ((m >> 1) & 3)) << 3) | (k4 & 4));
                *(int2*)&Ah[off] = make_int2((int)pack_hi(u0, u1), (int)pack_hi(u2, u3));
                *(int2*)&Al[off] = make_int2((int)pack_hi(r0, r1), (int)pack_hi(r2, r3));
            }
        }
    };

    stage(t0);
    __syncthreads();

    for (int t = t0; t < t1; ++t) {
        bf16x8 ah[4], al[4], bh[4], bl[4];
#pragma unroll
        for (int i = 0; i < 4; ++i) {
            const int mrow = (wr << 6) + (i << 4) + l16;
            const int ncol = (wc << 6) + (i << 4) + l16;
            ah[i] = *(const bf16x8*)&Ah[mrow * 32 + rchunk];
            if (useAl) al[i] = *(const bf16x8*)&Al[mrow * 32 + rchunk];
            bh[i] = *(const bf16x8*)&Bh[ncol * 32 + rchunk];
            bl[i] = *(const bf16x8*)&Bl[ncol * 32 + rchunk];
        }
        __syncthreads();                  // all waves done reading tile t
        if (t + 1 < t1) stage(t + 1);     // overwrite same buffers (async)
#pragma unroll
        for (int nt = 0; nt < 4; ++nt)
#pragma unroll
            for (int mt = 0; mt < 4; ++mt) {
                acc[mt][nt] = __builtin_amdgcn_mfma_f32_16x16x32_bf16(ah[mt], bh[nt], acc[mt][nt], 0, 0, 0);
                acc[mt][nt] = __builtin_amdgcn_mfma_f32_16x16x32_bf16(ah[mt], bl[nt], acc[mt][nt], 0, 0, 0);
                if (useAl)
                    acc[mt][nt] = __builtin_amdgcn_mfma_f32_16x16x32_bf16(al[mt], bh[nt], acc[mt][nt], 0, 0, 0);
            }
        __syncthreads();                  // drain staging (vmcnt0/lgkm0)
    }

    if (Cf && Z > 1) {                    // K-split: raw partial slab store
        float* dst = Cf + (long)zb * partStride;
#pragma unroll
        for (int mt = 0; mt < 4; ++mt)
#pragma unroll
            for (int nt = 0; nt < 4; ++nt) {
                const int col = col0 + (wc << 6) + (nt << 4) + l16;
#pragma unroll
                for (int rg = 0; rg < 4; ++rg) {
                    const int row = row0 + (wr << 6) + (mt << 4) + (q << 2) + rg;
                    dst[(long)row * N + col] = acc[mt][nt][rg];
                }
            }
        return;
    }

    if (Cpool) {
#pragma unroll
        for (int mt = 0; mt < 4; ++mt)
#pragma unroll
            for (int nt = 0; nt < 4; ++nt) {
                const int col = col0 + (wc << 6) + (nt << 4) + l16;
                float m = fmaxf(fmaxf(acc[mt][nt][0], acc[mt][nt][1]),
                                fmaxf(acc[mt][nt][2], acc[mt][nt][3]));
                m = fmaxf(m, __shfl_xor(m, 16));
                m = fmaxf(m, __shfl_xor(m, 32));
                m += bias[col];
                if (relu) m = fmaxf(m, 0.f);
                if (q == 0)
                    Cpool[(long)((row0 >> 4) + (wr << 2) + mt) * 768 + col] = m;
            }
        return;
    }
#pragma unroll
    for (int mt = 0; mt < 4; ++mt)
#pragma unroll
        for (int nt = 0; nt < 4; ++nt) {
            const int col = col0 + (wc << 6) + (nt << 4) + l16;
            const float bs = bias[col];
#pragma unroll
            for (int rg = 0; rg < 4; ++rg) {
                const int row = row0 + (wr << 6) + (mt << 4) + (q << 2) + rg;
                float v = acc[mt][nt][rg] + bs;
                if (relu) v = fmaxf(v, 0.f);
                if (Cf) Cf[(long)row * N + col] = v;
                if (Cph || Cp768) {
                    short h, l; split1(v, h, l);
                    if (Cph) {
                        Cph[(long)row * KpadOut + col] = h;
                        Cpl[(long)row * KpadOut + col] = l;
                    }
                    if (Cp768) Cp768[(long)row * 768 + col] = h;
                }
            }
        }
    if (CoordC && Cph && colb == 0 && tid < 128) {
        const int r = row0 + tid;
        const long rb = (long)r * KpadOut;
        const long cb = (long)(cfBase + r) * 5;
#pragma unroll
        for (int d = 0; d < 4; ++d) {
            short h, l; split1(CoordC[cb + 1 + d], h, l);
            Cph[rb + 768 + d] = h;
            Cpl[rb + 768 + d] = l;
        }
        for (int c = 772; c < 800; ++c) { Cph[rb + c] = 0; Cpl[rb + c] = 0; }
    }
}

// ---------------------------------------------------------------------------
// LayerNorm over K-split partials: z = relu(sum_z Fp[z] + bias45), then LN.
// 8 rows/block (4 waves x 2 rows), grid ch/8.
// ---------------------------------------------------------------------------
__global__ __launch_bounds__(256) void ln_kernel(const float* __restrict__ Fp,
                                                 long pstride,
                                                 const float* __restrict__ g,
                                                 const float* __restrict__ b,
                                                 const float* __restrict__ badd,
                                                 short* __restrict__ hp,
                                                 short* __restrict__ lp)
{
    const int tid = threadIdx.x, wave = tid >> 6, lane = tid & 63;
    float gv[4], bv[4], av[4];
#pragma unroll
    for (int j = 0; j < 4; ++j) {
        gv[j] = g[lane * 4 + j]; bv[j] = b[lane * 4 + j]; av[j] = badd[lane * 4 + j];
    }
    for (int i = 0; i < 2; ++i) {
        const int r = (blockIdx.x << 3) + (wave << 1) + i;
        const long off = (long)r * 256 + lane * 4;
        float4 x = *(const float4*)&Fp[off];
#pragma unroll
        for (int z = 1; z < ZSPLIT; ++z) {
            const float4 p = *(const float4*)&Fp[(long)z * pstride + off];
            x.x += p.x; x.y += p.y; x.z += p.z; x.w += p.w;
        }
        x.x = fmaxf(x.x + av[0], 0.f);
        x.y = fmaxf(x.y + av[1], 0.f);
        x.z = fmaxf(x.z + av[2], 0.f);
        x.w = fmaxf(x.w + av[3], 0.f);
        float s = x.x + x.y + x.z + x.w;
#pragma unroll
        for (int off2 = 32; off2; off2 >>= 1) s += __shfl_down(s, off2);
        const float mu = __shfl(s, 0) * (1.f / 256.f);
        const float d0 = x.x - mu, d1 = x.y - mu, d2 = x.z - mu, d3 = x.w - mu;
        float s2 = d0 * d0 + d1 * d1 + d2 * d2 + d3 * d3;
#pragma unroll
        for (int off2 = 32; off2; off2 >>= 1) s2 += __shfl_down(s2, off2);
        const float den = sqrtf(__shfl(s2, 0) * (1.f / 256.f) + 1e-5f);
        const float v[4] = { d0 / den * gv[0] + bv[0], d1 / den * gv[1] + bv[1],
                             d2 / den * gv[2] + bv[2], d3 / den * gv[3] + bv[3] };
#pragma unroll
        for (int j = 0; j < 4; ++j) {
            short h, l; split1(v[j], h, l);
            hp[(long)r * 256 + lane * 4 + j] = h;
            lp[(long)r * 256 + lane * 4 + j] = l;
        }
    }
}

// ---------------------------------------------------------------------------
// imp over K-split partials: z2 = relu(sum_z Fp[z] + ib2), then iw3 dot.
// 8 rows/block, grid ch/8.
// ---------------------------------------------------------------------------
__global__ __launch_bounds__(256) void imp_kernel(const float* __restrict__ Fp,
                                                  long pstride,
                                                  const float* __restrict__ iw3,
                                                  const float* __restrict__ ib3,
                                                  const float* __restrict__ ib2,
                                                  const float* __restrict__ noise,
                                                  const float* __restrict__ lt,
                                                  float* __restrict__ pert,
                                                  int base)
{
    const int tid = threadIdx.x, wave = tid >> 6, lane = tid & 63;
    float wv[4], bv[4];
#pragma unroll
    for (int j = 0; j < 4; ++j) { wv[j] = iw3[lane * 4 + j]; bv[j] = ib2[lane * 4 + j]; }
    const float temp = fmaxf(expf(lt[0]), 0.1f);
    const float b3v = ib3[0];
    for (int i = 0; i < 2; ++i) {
        const int r = (blockIdx.x << 3) + (wave << 1) + i;
        const long off = (long)r * 256 + lane * 4;
        float4 x = *(const float4*)&Fp[off];
#pragma unroll
        for (int z = 1; z < ZSPLIT; ++z) {
            const float4 p = *(const float4*)&Fp[(long)z * pstride + off];
            x.x += p.x; x.y += p.y; x.z += p.z; x.w += p.w;
        }
        float s = fmaxf(x.x + bv[0], 0.f) * wv[0] + fmaxf(x.y + bv[1], 0.f) * wv[1]
                + fmaxf(x.z + bv[2], 0.f) * wv[2] + fmaxf(x.w + bv[3], 0.f) * wv[3];
#pragma unroll
        for (int off2 = 32; off2; off2 >>= 1) s += __shfl_down(s, off2);
        if (lane == 0)
            pert[base + r] = (s + b3v + noise[base + r]) / temp;
    }
}

// ---------------------------------------------------------------------------
// top-128, two-phase (exact):
//  phase 1 (topk_part): 64 blocks = 8 events x 8 slices of 2048 points.
//    v2: RADIX SELECT instead of full 2048-bitonic (78us -> ~12us).
//    Values held in registers (8/thread); 8-bit MSB histogram -> threshold
//    bucket b; all keys with bucket>b (cgt<128) + top-(128-cgt) of bucket b
//    (<=256-elem bitonic, serial fallback if heavy ties). Output UNSORTED —
//    topk_merge sorts the union, so only the SET must be exact (same total
//    order key fmap(v)<<32|~idx as the verified single-block radix).
//  phase 2 (topk_merge): 8 blocks; bitonic-sort the 1024 candidates.
// ---------------------------------------------------------------------------
__device__ __forceinline__ unsigned fmap(float f) {
    unsigned x = __float_as_uint(f);
    return (x & 0x80000000u) ? ~x : (x | 0x80000000u);
}

__global__ __launch_bounds__(256) void topk_part(const float* __restrict__ pert,
                                                 unsigned long long* __restrict__ cand)
{
    const int e = blockIdx.x >> 3, s = blockIdx.x & 7, tid = threadIdx.x;
    const int base = e * PPE + s * 2048;
    const int c4 = tid & 3;
    __shared__ unsigned hist4[1024];             // x4-replicated 256-bin hist
    __shared__ unsigned long long gt[MT];
    __shared__ unsigned long long eqk[256];
    __shared__ int cgt, ceq, sh_need;
    __shared__ unsigned sh_b;
    unsigned u[8];
#pragma unroll
    for (int i = 0; i < 8; ++i)
        u[i] = fmap(pert[base + (i << 8) + tid]);
    for (int i = tid; i < 1024; i += 256) hist4[i] = 0;
    if (tid == 0) { cgt = 0; ceq = 0; }
    __syncthreads();
#pragma unroll
    for (int i = 0; i < 8; ++i)
        atomicAdd(&hist4[((u[i] >> 24) << 2) | c4], 1u);
    __syncthreads();
    if (tid == 0) {
        int cum = 0, b = 255, cb = 0;
        for (; b > 0; --b) {
            cb = (int)(hist4[b << 2] + hist4[(b << 2) | 1]
                     + hist4[(b << 2) | 2] + hist4[(b << 2) | 3]);
            cum += cb;
            if (cum >= MT) break;
        }
        if (cum < MT) {
            cb = (int)(hist4[0] + hist4[1] + hist4[2] + hist4[3]);
            cum += cb; b = 0;
        }
        sh_need = MT - (cum - cb);
        sh_b = (unsigned)b;
    }
    __syncthreads();
    const unsigned bb = sh_b;
    const int need = sh_need;
#pragma unroll
    for (int i = 0; i < 8; ++i) {
        const unsigned bkt = u[i] >> 24;
        const int idx = base + (i << 8) + tid;
        const unsigned long long kk =
            ((unsigned long long)u[i] << 32) | (unsigned)(~idx);
        if (bkt > bb)        { int q = atomicAdd(&cgt, 1); if (q < MT)  gt[q]  = kk; }
        else if (bkt == bb)  { int q = atomicAdd(&ceq, 1); if (q < 256) eqk[q] = kk; }
    }
    __syncthreads();
    const int ngt = (cgt < MT) ? cgt : MT;       // by construction cgt < MT
    if (ceq <= 256) {
        if (tid >= ceq) eqk[tid] = 0ull;
        __syncthreads();
        for (int k = 2; k <= 256; k <<= 1)
            for (int j = k >> 1; j > 0; j >>= 1) {
                const int l = tid ^ j;
                if (l > tid) {
                    const unsigned long long a = eqk[tid], b = eqk[l];
                    const bool up = ((tid & k) == 0);
                    if (up ? (a < b) : (a > b)) { eqk[tid] = b; eqk[l] = a; }
                }
                __syncthreads();
            }
    } else {
        if (tid == 0) {                           // rare: heavy threshold ties
            unsigned long long sel[MT];
            int n = 0;
            for (int p = 0; p < 2048; ++p) {
                const unsigned uu = fmap(pert[base + p]);
                if ((uu >> 24) != bb) continue;
                const unsigned long long kk =
                    ((unsigned long long)uu << 32) | (unsigned)(~(base + p));
                if (n < need) {
                    int j = n++;
                    while (j > 0 && sel[j - 1] < kk) { sel[j] = sel[j - 1]; --j; }
                    sel[j] = kk;
                } else if (kk > sel[need - 1]) {
                    int j = need - 1;
                    while (j > 0 && sel[j - 1] < kk) { sel[j] = sel[j - 1]; --j; }
                    sel[j] = kk;
                }
            }
            for (int j = 0; j < need; ++j) eqk[j] = sel[j];
        }
        __syncthreads();
    }
    if (tid < MT)
        cand[(long)blockIdx.x * MT + tid] = (tid < ngt) ? gt[tid] : eqk[tid - ngt];
}

__global__ __launch_bounds__(256) void topk_merge(const unsigned long long* __restrict__ cand,
                                                  const float4* __restrict__ c4f,
                                                  float* __restrict__ centf)
{
    const int e = blockIdx.x, tid = threadIdx.x;
    __shared__ unsigned long long key[1024];     // 8 KB
    for (int i = tid; i < 1024; i += 256)
        key[i] = cand[(long)e * 1024 + i];
    __syncthreads();
    for (int k = 2; k <= 1024; k <<= 1)
        for (int j = k >> 1; j > 0; j >>= 1) {
            for (int i = tid; i < 1024; i += 256) {
                const int l = i ^ j;
                if (l > i) {
                    const unsigned long long a = key[i], b = key[l];
                    const bool up = ((i & k) == 0);
                    if (up ? (a < b) : (a > b)) { key[i] = b; key[l] = a; }
                }
            }
            __syncthreads();
        }
    if (tid < MT) {
        const int idx = (int)(~(unsigned)(key[tid] & 0xFFFFFFFFu));
        *(float4*)&centf[(long)(e * MT + tid) * 4] = c4f[idx];
    }
}

// ---------------------------------------------------------------------------
// 16-NN per (event,centroid): 2-level cached radix, x4-replicated histograms
// ---------------------------------------------------------------------------
__device__ __forceinline__ unsigned d2bits(const float4 x, float c0, float c1,
                                           float c2, float c3) {
    const float q0 = __fmul_rn(c0 - x.x, c0 - x.x);
    const float q1 = __fmul_rn(c1 - x.y, c1 - x.y);
    const float q2 = __fmul_rn(c2 - x.z, c2 - x.z);
    const float q3 = __fmul_rn(c3 - x.w, c3 - x.w);
    return __float_as_uint(__fadd_rn(__fadd_rn(__fadd_rn(q0, q1), q2), q3));
}

__global__ __launch_bounds__(256) void knn_kernel(const float4* __restrict__ c4f,
                                                  const float* __restrict__ centf,
                                                  int* __restrict__ knn_idx)
{
    const int blk = blockIdx.x, tid = threadIdx.x;
    const int e = blk >> 7, base = e * PPE;
    const int c4 = tid & 3;
    const float c0 = centf[(long)blk * 4 + 0];
    const float c1 = centf[(long)blk * 4 + 1];
    const float c2 = centf[(long)blk * 4 + 2];
    const float c3 = centf[(long)blk * 4 + 3];
    __shared__ unsigned short d16[PPE];          // 32 KB
    __shared__ unsigned long long ubuf[664];
    __shared__ int sh_need; __shared__ unsigned sh_b;
    __shared__ int clt, ceq;
    unsigned* hist4 = (unsigned*)ubuf;           // 1024
    unsigned* histm = hist4 + 1024;              // 256
    for (int i = tid; i < 1024; i += 256) hist4[i] = 0;
    __syncthreads();
    for (int p = tid; p < PPE; p += 256) {
        const unsigned u = d2bits(c4f[base + p], c0, c1, c2, c3);
        d16[p] = (unsigned short)(u >> 16);
        atomicAdd(&hist4[((u >> 24) << 2) | c4], 1u);
    }
    __syncthreads();
    histm[tid] = hist4[tid << 2] + hist4[(tid << 2) | 1]
               + hist4[(tid << 2) | 2] + hist4[(tid << 2) | 3];
    __syncthreads();
    if (tid == 0) {
        int cum = 0, b = 0;
        for (; b < 255; ++b) { cum += (int)histm[b]; if (cum >= KNN) break; }
        if (cum < KNN) { cum += (int)histm[255]; b = 255; }
        sh_need = KNN - (cum - (int)histm[b]); sh_b = (unsigned)b;
    }
    __syncthreads();
    int need = sh_need;
    const unsigned b1v = sh_b;
    __syncthreads();
    for (int i = tid; i < 1024; i += 256) hist4[i] = 0;
    __syncthreads();
    for (int p = tid; p < PPE; p += 256) {
        const unsigned h = d16[p];
        if ((h >> 8) == b1v) atomicAdd(&hist4[((h & 255u) << 2) | c4], 1u);
    }
    __syncthreads();
    histm[tid] = hist4[tid << 2] + hist4[(tid << 2) | 1]
               + hist4[(tid << 2) | 2] + hist4[(tid << 2) | 3];
    __syncthreads();
    if (tid == 0) {
        int cum = 0, b = 0;
        for (; b < 255; ++b) { cum += (int)histm[b]; if (cum >= need) break; }
        if (cum < need) { cum += (int)histm[255]; b = 255; }
        sh_need = need - (cum - (int)histm[b]); sh_b = (unsigned)b;
    }
    __syncthreads();
    need = sh_need;
    const unsigned prefix16 = (b1v << 8) | sh_b;
    // ---- collect phase: re-carve ubuf
    int* lt_i = (int*)ubuf;                                   // 16
    unsigned* lt_u = (unsigned*)(lt_i + KNN);                 // 16
    int* eqbuf = (int*)(lt_u + KNN);                          // 256
    unsigned long long* key256 = (unsigned long long*)(eqbuf + 256);  // 256
    if (tid == 0) { clt = 0; ceq = 0; }
    __syncthreads();
    for (int p = tid; p < PPE; p += 256) {
        const unsigned h = d16[p];
        if (h < prefix16)        { int q = atomicAdd(&clt, 1); if (q < KNN) lt_i[q] = p; }
        else if (h == prefix16)  { int q = atomicAdd(&ceq, 1); if (q < 256) eqbuf[q] = p; }
    }
    __syncthreads();
    const int nlt = (clt < KNN) ? clt : KNN;
    if (tid < nlt) lt_u[tid] = d2bits(c4f[base + lt_i[tid]], c0, c1, c2, c3);
    if (ceq <= 256) {
        key256[tid] = (tid < ceq)
            ? (((unsigned long long)d2bits(c4f[base + eqbuf[tid]], c0, c1, c2, c3) << 32)
               | (unsigned)eqbuf[tid])
            : 0xFFFFFFFFFFFFFFFFull;
        __syncthreads();
        for (int k = 2; k <= 256; k <<= 1)
            for (int j = k >> 1; j > 0; j >>= 1) {
                const int l = tid ^ j;
                if (l > tid) {
                    const unsigned long long a = key256[tid], b = key256[l];
                    const bool up = ((tid & k) == 0);
                    if (up ? (a > b) : (a < b)) { key256[tid] = b; key256[l] = a; }
                }
                __syncthreads();
            }
    } else if (tid == 0) {
        unsigned long long sel[KNN];
        int n = 0;
        for (int p = 0; p < PPE; ++p) {
            if (d16[p] != (unsigned short)prefix16) continue;
            const unsigned long long kk =
                ((unsigned long long)d2bits(c4f[base + p], c0, c1, c2, c3) << 32) | (unsigned)p;
            if (n < need) {
                int j = n++;
                while (j > 0 && sel[j - 1] > kk) { sel[j] = sel[j - 1]; --j; }
                sel[j] = kk;
            } else if (kk < sel[need - 1]) {
                int j = need - 1;
                while (j > 0 && sel[j - 1] > kk) { sel[j] = sel[j - 1]; --j; }
                sel[j] = kk;
            }
        }
        for (int j = 0; j < need; ++j) key256[j] = sel[j];
    }
    __syncthreads();
    if (tid == 0) {
        unsigned long long fin[KNN];
        int n = 0;
        for (int i = 0; i < nlt; ++i) {
            const unsigned long long kk = ((unsigned long long)lt_u[i] << 32) | (unsigned)lt_i[i];
            int j = n++;
            while (j > 0 && fin[j - 1] > kk) { fin[j] = fin[j - 1]; --j; }
            fin[j] = kk;
        }
        for (int i = 0; i < need; ++i) {
            const unsigned long long kk = key256[i];
            int j = n++;
            while (j > 0 && fin[j - 1] > kk) { fin[j] = fin[j - 1]; --j; }
            fin[j] = kk;
        }
        for (int r = 0; r < KNN; ++r)
            knn_idx[blk * KNN + r] = base + (int)(unsigned)(fin[r] & 0xFFFFFFFFu);
    }
}

// ---------------------------------------------------------------------------
// emit parallel: grid (BATCH, 16)
// ---------------------------------------------------------------------------
__global__ __launch_bounds__(256) void emit_kernel(const float* __restrict__ centf,
                                                   const float* __restrict__ tokf,
                                                   float* __restrict__ out,
                                                   long out_size)
{
    const int e = blockIdx.x, s = blockIdx.y, tid = threadIdx.x;
    __shared__ float tv[MT];
    __shared__ int   rk[MT];
    if (tid < MT) tv[tid] = centf[(long)(e * MT + tid) * 4 + 3];
    __syncthreads();
    if (tid < MT) {
        const float t = tv[tid]; int r = 0;
        for (int j = 0; j < MT; ++j)
            r += (tv[j] < t || (tv[j] == t && j < tid)) ? 1 : 0;
        rk[tid] = r;
    }
    __syncthreads();
    const long cent_off = (long)BATCH * MT * TOKD;
    const long mask_off = cent_off + (long)BATCH * MT * 4;
    for (int i = s * 8; i < s * 8 + 8; ++i) {
        const float* src = tokf + ((size_t)e * MT + i) * TOKD;
        const long dst = ((long)e * MT + rk[i]) * TOKD;
        for (int t4 = tid; t4 < TOKD / 4; t4 += 256) {
            const float4 v = ((const float4*)src)[t4];
            const long g = dst + (long)t4 * 4;
            if (g + 3 < out_size) {
                *(float4*)&out[g] = v;
            } else {
                if (g + 0 < out_size) out[g + 0] = v.x;
                if (g + 1 < out_size) out[g + 1] = v.y;
                if (g + 2 < out_size) out[g + 2] = v.z;
                if (g + 3 < out_size) out[g + 3] = v.w;
            }
        }
    }
    if (s == 0) {
        for (int idx = tid; idx < MT * 4; idx += 256) {
            const int i = idx >> 2, d = idx & 3;
            const long g = cent_off + ((long)e * MT + rk[i]) * 4 + d;
            if (g < out_size) out[g] = centf[((long)e * MT + i) * 4 + d];
        }
        for (int idx = tid; idx < MT; idx += 256) {
            const long g = mask_off + (long)e * MT + idx;
            if (g < out_size) out[g] = 1.0f;
        }
    }
}

// ---------------------------------------------------------------------------
extern "C" void kernel_launch(void* const* d_in, const int* in_sizes, int n_in,
                              void* d_out, int out_size, void* d_ws, size_t ws_size,
                              hipStream_t stream)
{
    const float* coords = (const float*)d_in[0];
    const float* feats  = (const float*)d_in[1];
    const float* lt     = (const float*)d_in[2];
    const float* w1  = (const float*)d_in[3];  const float* b1  = (const float*)d_in[4];
    const float* w2  = (const float*)d_in[5];  const float* b2  = (const float*)d_in[6];
    const float* w3  = (const float*)d_in[7];  const float* b3  = (const float*)d_in[8];
    const float* w4  = (const float*)d_in[9];  const float* b4  = (const float*)d_in[10];
    const float* iw1 = (const float*)d_in[11]; const float* ib1 = (const float*)d_in[12];
    const float* lng = (const float*)d_in[13]; const float* lnb = (const float*)d_in[14];
    const float* iw2 = (const float*)d_in[15]; const float* ib2 = (const float*)d_in[16];
    const float* iw3 = (const float*)d_in[17]; const float* ib3 = (const float*)d_in[18];
    const float* nw1 = (const float*)d_in[19]; const float* nb1 = (const float*)d_in[20];
    const float* nw2 = (const float*)d_in[21]; const float* nb2 = (const float*)d_in[22];
    const float* noise = (const float*)d_in[23];

    const int NBR = BATCH * MT * KNN;   // 16384
    const size_t FIXED_FL = (size_t)NPT + 4096 + 16384 + 16384 + (size_t)1024 * TOKD
                          + (size_t)NPT * 4 + 256 + 2 * (size_t)1024 * TOKD;
    const size_t s_w2 = 512 * 256,  s_w3 = 768 * 512,  s_w4 = 768 * 768;
    const size_t s_45 = 256 * 800,  s_i2 = 256 * 256;
    const size_t s_n1 = 768 * 768,  s_n2 = 768 * 768;
    const size_t WTOT = 2 * (s_w2 + s_w3 + s_w4 + s_45 + s_i2 + s_n1 + s_n2);
    const size_t BASE_BYTES = FIXED_FL * 4 + WTOT * 2;
    // per-row: PA pair (800 wide) + PB pair (512 wide) + Fp slabs (Z x 256 f32)
    const size_t PERROW = (800 * 2 + 512 * 2) * 2 + (size_t)ZSPLIT * 256 * 4;  // 7296
    int ch = 128;
    // Uncapped doubling (round-8 verified best: ch=65536 @ 1673us beat the
    // CHMAX=16384 L3-residency cap @ 1801us — HBM absorbs activation traffic
    // at 1.8 TB/s; launch count/grid size dominate).
    while (ch < NPT && BASE_BYTES + (size_t)(ch * 2) * PERROW <= ws_size) ch <<= 1;
    const size_t H3_BYTES = (size_t)NPT * 768 * 2;
    const bool persist = (BASE_BYTES + (size_t)ch * PERROW + H3_BYTES) <= ws_size;

    float*  pert   = (float*)d_ws;
    float*  centf  = pert + NPT;
    int*    knn    = (int*)(centf + 4096);
    unsigned long long* cand = (unsigned long long*)(knn + 16384);   // 8192 u64
    float*  pooled = (float*)(cand + 8192);
    float4* c4f    = (float4*)(pooled + (size_t)1024 * TOKD);
    float*  bias45 = (float*)(c4f + NPT);
    float*  T1     = bias45 + 256;                      // 1024*768
    float*  T2     = T1 + (size_t)1024 * TOKD;          // 1024*768
    short*  wsp    = (short*)(T2 + (size_t)1024 * TOKD);
    short* w2h = wsp;            short* w2l = w2h + s_w2;
    short* w3h = w2l + s_w2;     short* w3l = w3h + s_w3;
    short* w4h = w3l + s_w3;     short* w4l = w4h + s_w4;
    short* f45h = w4l + s_w4;    short* f45l = f45h + s_45;
    short* i2h = f45l + s_45;    short* i2l = i2h + s_i2;
    short* n1h = i2l + s_i2;     short* n1l = n1h + s_n1;
    short* n2h = n1l + s_n1;     short* n2l = n2h + s_n2;
    short* PAh = n2l + s_n2;     short* PAl = PAh + (size_t)ch * 800;
    short* PBh = PAl + (size_t)ch * 800;
    short* PBl = PBh + (size_t)ch * 512;
    float* Fp  = (float*)(PBl + (size_t)ch * 512);      // ZSPLIT x ch x 256 fp32
    short* H3  = (short*)(Fp + (size_t)ZSPLIT * ch * 256);  // NPT*768 bf16-hi (opt)
    const long pstride = (long)ch * 256;

    prep_kernel<<<dim3((NPT + 255) / 256), dim3(256), 0, stream>>>(coords, c4f);
    wsplit_all<<<dim3(3840), dim3(256), 0, stream>>>(
        w2, w3, w4, iw2, nw1, nw2,
        w2h, w2l, w3h, w3l, w4h, w4l, i2h, i2l, n1h, n1l, n2h, n2l);
    w45_kernel<<<dim3(801), dim3(256), 0, stream>>>(w4, iw1, b4, ib1, f45h, f45l, bias45);

    for (int ck = 0; ck < NPT / ch; ++ck) {
        const int base = ck * ch;
        l1_kernel<<<dim3(ch / 64), dim3(256), 0, stream>>>(feats, w1, b1, PAh, PAl, base, nullptr);
        gemm_mf<<<dim3(512 / 128, ch / 128), dim3(256), 0, stream>>>(
            PAh, PAl, nullptr, 256, w2h, w2l, b2, PBh, PBl, 512,
            nullptr, nullptr, nullptr, nullptr, 0, 512, 1, 0);
        gemm_mf<<<dim3(768 / 128, ch / 128), dim3(256), 0, stream>>>(
            PBh, PBl, nullptr, 512, w3h, w3l, b3, PAh, PAl, 800,
            nullptr, persist ? (H3 + (size_t)base * 768) : nullptr, nullptr,
            coords, base, 768, 1, 0);
        // K-split x ZSPLIT, non-atomic partial slabs into Fp
        gemm_mf<<<dim3(256 / 128, ch / 128, ZSPLIT), dim3(256), 0, stream>>>(
            PAh, PAl, nullptr, 800, f45h, f45l, nullptr, nullptr, nullptr, 0,
            Fp, nullptr, nullptr, nullptr, 0, 256, 0, pstride);
        ln_kernel<<<dim3(ch / 8), dim3(256), 0, stream>>>(
            Fp, pstride, lng, lnb, bias45, PBh, PBl);
        gemm_mf<<<dim3(256 / 128, ch / 128, ZSPLIT), dim3(256), 0, stream>>>(
            PBh, PBl, nullptr, 256, i2h, i2l, nullptr, nullptr, nullptr, 0,
            Fp, nullptr, nullptr, nullptr, 0, 256, 0, pstride);
        imp_kernel<<<dim3(ch / 8), dim3(256), 0, stream>>>(
            Fp, pstride, iw3, ib3, ib2, noise, lt, pert, base);
    }

    topk_part<<<dim3(BATCH * 8), dim3(256), 0, stream>>>(pert, cand);
    topk_merge<<<dim3(BATCH), dim3(256), 0, stream>>>(cand, c4f, centf);
    knn_kernel<<<dim3(BATCH * MT), dim3(256), 0, stream>>>(c4f, centf, knn);

    const int rcch = (ch < NBR) ? ch : NBR;
    for (int rc = 0; rc < NBR / rcch; ++rc) {
        if (persist) {
            gather_h3_kernel<<<dim3(rcch), dim3(256), 0, stream>>>(
                H3, knn, rc * rcch, PAh);
            gemm_mf<<<dim3(768 / 128, rcch / 128), dim3(256), 0, stream>>>(
                PAh, nullptr, nullptr, 768, w4h, w4l, b4, nullptr, nullptr, 0,
                nullptr, nullptr, pooled + (size_t)(rc * rcch / 16) * 768,
                nullptr, 0, 768, 0, 0);
        } else {
            l1_kernel<<<dim3(rcch / 64), dim3(256), 0, stream>>>(feats, w1, b1, PAh, PAl, 0, knn + (size_t)rc * rcch);
            gemm_mf<<<dim3(512 / 128, rcch / 128), dim3(256), 0, stream>>>(
                PAh, PAl, nullptr, 256, w2h, w2l, b2, PBh, PBl, 512,
                nullptr, nullptr, nullptr, nullptr, 0, 512, 1, 0);
            gemm_mf<<<dim3(768 / 128, rcch / 128), dim3(256), 0, stream>>>(
                PBh, PBl, nullptr, 512, w3h, w3l, b3, PAh, PAl, 768,
                nullptr, nullptr, nullptr, nullptr, 0, 768, 1, 0);
            gemm_mf<<<dim3(768 / 128, rcch / 128), dim3(256), 0, stream>>>(
                PAh, PAl, nullptr, 768, w4h, w4l, b4, nullptr, nullptr, 0,
                nullptr, nullptr, pooled + (size_t)(rc * rcch / 16) * 768,
                nullptr, 0, 768, 0, 0);
        }
    }

    // ---- token MLP (1024x768, fp32-A) + parallel emit ----
    gemm_mf<<<dim3(768 / 128, 1024 / 128), dim3(256), 0, stream>>>(
        nullptr, nullptr, pooled, 768, n1h, n1l, nb1, nullptr, nullptr, 0,
        T1, nullptr, nullptr, nullptr, 0, 768, 1, 0);
    gemm_mf<<<dim3(768 / 128, 1024 / 128), dim3(256), 0, stream>>>(
        nullptr, nullptr, T1, 768, n2h, n2l, nb2, nullptr, nullptr, 0,
        T2, nullptr, nullptr, nullptr, 0, 768, 0, 0);
    emit_kernel<<<dim3(BATCH, 16), dim3(256), 0, stream>>>(
        centf, T2, (float*)d_out, (long)out_size);
}

// Round 13
// 1642.598 us; speedup vs baseline: 2.2180x; 2.2180x over previous
//
#include <hip/hip_runtime.h>
#include <hip/hip_bf16.h>

// GumbelSoftmaxTokenizer: B=8, P=16384, FEAT=6, TOK=768, MT=128, K=16, IH=256
// All inputs float32; output buffer float32 (tokens, cents, masks concat).
#define NPT   131072      // B*P
#define BATCH 8
#define PPE   16384
#define MT    128
#define KNN   16
#define TOKD  768
#define ZSPLIT 2          // K-split factor for the IH=256 GEMMs

typedef short bf16x8 __attribute__((ext_vector_type(8)));
typedef float f32x4  __attribute__((ext_vector_type(4)));

#define GL16(g, l) __builtin_amdgcn_global_load_lds(                         \
    (const __attribute__((address_space(1))) void*)(g),                      \
    (__attribute__((address_space(3))) void*)(l), 16, 0, 0)

__device__ __forceinline__ unsigned pack_hi(unsigned u0, unsigned u1) {
    return (u0 >> 16) | (u1 & 0xFFFF0000u);
}
__device__ __forceinline__ void split1(float x, short& h, short& l) {
    const unsigned u = __float_as_uint(x);
    h = (short)(u >> 16);
    const float r = x - __uint_as_float(u & 0xFFFF0000u);
    l = (short)(__float_as_uint(r) >> 16);
}

// ---------------------------------------------------------------------------
// prep: c4f[i] = coords[i,1:5] packed float4
// ---------------------------------------------------------------------------
__global__ __launch_bounds__(256) void prep_kernel(const float* __restrict__ coords,
                                                   float4* __restrict__ c4f)
{
    const int i = blockIdx.x * 256 + threadIdx.x;
    if (i < NPT) {
        const long b = (long)i * 5;
        c4f[i] = make_float4(coords[b + 1], coords[b + 2], coords[b + 3], coords[b + 4]);
    }
}

// ---------------------------------------------------------------------------
// All weight pre-converts in ONE launch (segments by blockIdx)
// ---------------------------------------------------------------------------
__global__ __launch_bounds__(256) void wsplit_all(
    const float* __restrict__ w2, const float* __restrict__ w3,
    const float* __restrict__ w4, const float* __restrict__ iw2,
    const float* __restrict__ nw1, const float* __restrict__ nw2,
    short* w2h, short* w2l, short* w3h, short* w3l,
    short* w4h, short* w4l, short* i2h, short* i2l,
    short* n1h, short* n1l, short* n2h, short* n2l)
{
    const int b = blockIdx.x;
    const float* W; int K, N, Kpad, n; short *hi, *lo;
    if (b < 512)       { W = w2;  K = 256; N = 512; Kpad = 256; hi = w2h; lo = w2l; n = b; }
    else if (b < 1280) { W = w3;  K = 512; N = 768; Kpad = 512; hi = w3h; lo = w3l; n = b - 512; }
    else if (b < 2048) { W = w4;  K = 768; N = 768; Kpad = 768; hi = w4h; lo = w4l; n = b - 1280; }
    else if (b < 2304) { W = iw2; K = 256; N = 256; Kpad = 256; hi = i2h; lo = i2l; n = b - 2048; }
    else if (b < 3072) { W = nw1; K = 768; N = 768; Kpad = 768; hi = n1h; lo = n1l; n = b - 2304; }
    else               { W = nw2; K = 768; N = 768; Kpad = 768; hi = n2h; lo = n2l; n = b - 3072; }
    for (int k = threadIdx.x; k < Kpad; k += 256) {
        short h = 0, l = 0;
        if (k < K) split1(W[(long)k * N + n], h, l);
        hi[(long)n * Kpad + k] = h;
        lo[(long)n * Kpad + k] = l;
    }
}

// ---------------------------------------------------------------------------
// W45 fusion, parallel form: 801 blocks.
// ---------------------------------------------------------------------------
__global__ __launch_bounds__(256) void w45_kernel(const float* __restrict__ w4,
                                                  const float* __restrict__ iw1,
                                                  const float* __restrict__ b4,
                                                  const float* __restrict__ ib1,
                                                  short* __restrict__ hi,
                                                  short* __restrict__ lo,
                                                  float* __restrict__ bias45)
{
    const int k = blockIdx.x, n = threadIdx.x;
    if (k < 768) {
        const float* wr = w4 + (long)k * 768;
        float v0 = 0.f, v1 = 0.f, v2 = 0.f, v3 = 0.f;
        for (int j = 0; j < 768; j += 4) {
            v0 += wr[j]     * iw1[(long)j * 256 + n];
            v1 += wr[j + 1] * iw1[(long)(j + 1) * 256 + n];
            v2 += wr[j + 2] * iw1[(long)(j + 2) * 256 + n];
            v3 += wr[j + 3] * iw1[(long)(j + 3) * 256 + n];
        }
        const float v = (v0 + v1) + (v2 + v3);
        short h, l; split1(v, h, l);
        hi[(long)n * 800 + k] = h;
        lo[(long)n * 800 + k] = l;
    } else if (k < 800) {
        const float v = (k < 772) ? iw1[(long)k * 256 + n] : 0.f;
        short h, l; split1(v, h, l);
        hi[(long)n * 800 + k] = h;
        lo[(long)n * 800 + k] = l;
    } else {
        float v0 = 0.f, v1 = 0.f, v2 = 0.f, v3 = 0.f;
        for (int j = 0; j < 768; j += 4) {
            v0 += b4[j]     * iw1[(long)j * 256 + n];
            v1 += b4[j + 1] * iw1[(long)(j + 1) * 256 + n];
            v2 += b4[j + 2] * iw1[(long)(j + 2) * 256 + n];
            v3 += b4[j + 3] * iw1[(long)(j + 3) * 256 + n];
        }
        bias45[n] = (v0 + v1) + (v2 + v3) + ib1[n];
    }
}

// ---------------------------------------------------------------------------
// L1 multi-row: 64 rows/block
// ---------------------------------------------------------------------------
__global__ __launch_bounds__(256) void l1_kernel(const float* __restrict__ f,
                                                 const float* __restrict__ w1,
                                                 const float* __restrict__ b1,
                                                 short* __restrict__ hp,
                                                 short* __restrict__ lp,
                                                 int base,
                                                 const int* __restrict__ gather)
{
    const int r0 = blockIdx.x << 6, tid = threadIdx.x;
    float wc[6];
#pragma unroll
    for (int k = 0; k < 6; ++k) wc[k] = w1[k * 256 + tid];
    const float bb = b1[tid];
    for (int i = 0; i < 64; ++i) {
        const int r = r0 + i;
        int row = gather ? gather[r] : (base + r);
        row = (row < 0) ? 0 : ((row >= NPT) ? (NPT - 1) : row);
        float acc = bb;
#pragma unroll
        for (int k = 0; k < 6; ++k) acc += f[(long)row * 6 + k] * wc[k];
        acc = fmaxf(acc, 0.f);
        short h, l; split1(acc, h, l);
        hp[(long)r * 256 + tid] = h;
        lp[(long)r * 256 + tid] = l;
    }
}

// ---------------------------------------------------------------------------
// gather_h3: G[i][0:768] = H3[knn[off+i]][0:768]
// ---------------------------------------------------------------------------
__global__ __launch_bounds__(256) void gather_h3_kernel(const short* __restrict__ H3,
                                                        const int* __restrict__ knn_idx,
                                                        int off,
                                                        short* __restrict__ G)
{
    const int i = blockIdx.x;
    const int row = knn_idx[off + i];
    const int4* src = (const int4*)(H3 + (long)row * 768);
    int4* dst = (int4*)(G + (long)i * 768);
    if (threadIdx.x < 96) dst[threadIdx.x] = src[threadIdx.x];
}

// ---------------------------------------------------------------------------
// Split-bf16 MFMA GEMM, 128x128 tile, 4 waves in 2x2 (wave = 64x64 sub-tile).
// K-SPLIT (non-atomic): Z = gridDim.z; block z computes K-steps
// [nk*z/Z, nk*(z+1)/Z) and stores RAW fp32 partials (no bias/relu) to
// Cf + z*partStride with plain coalesced stores. Consumer sums the Z slabs.
// Phase order per K-step (T3-minimum): ds_read frags -> barrier ->
// stage(t+1) -> MFMA -> barrier (drain hides under compute).
// LDS XOR-swizzled (0 bank conflicts, verified r1-r2).
// launch_bounds(256,3): VERIFIED config (84 VGPR, no spill). (256,5) forces
// the 8-wave VGPR step (<=64) -> 48 VGPR -> acc[] spills to scratch
// (FETCH 590MB/WRITE 939MB per dispatch, 4x regression — round 10).
// ---------------------------------------------------------------------------
__global__ __launch_bounds__(256, 3) void gemm_mf(
    const short* __restrict__ Aph, const short* __restrict__ Apl,
    const float* __restrict__ Afp, int Kpad,
    const short* __restrict__ Wth, const short* __restrict__ Wtl,
    const float* __restrict__ bias,
    short* __restrict__ Cph, short* __restrict__ Cpl, int KpadOut,
    float* __restrict__ Cf, short* __restrict__ Cp768,
    float* __restrict__ Cpool,
    const float* __restrict__ CoordC, int cfBase,
    int N, int relu, long partStride)
{
    __shared__ short Ah[128 * 32];
    __shared__ short Al[128 * 32];
    __shared__ short Bh[128 * 32];
    __shared__ short Bl[128 * 32];
    const int tid = threadIdx.x;
    int rowb, colb;
    {
        const int ncol = gridDim.x, nrow = gridDim.y;
        if ((nrow & 7) == 0) {
            const int id  = blockIdx.y * ncol + blockIdx.x;
            const int sgs = ncol << 3;
            const int sg = id / sgs, wi = id % sgs;
            rowb = (sg << 3) + (wi & 7);
            colb = wi >> 3;
        } else { rowb = blockIdx.y; colb = blockIdx.x; }
    }
    const int row0 = rowb << 7, col0 = colb << 7;
    const int wave = tid >> 6, lane = tid & 63;
    const int wr = wave >> 1, wc = wave & 1;
    const int q = lane >> 4, l16 = lane & 15;
    const int l2 = lane >> 2;
    // staging source chunk (pre-swizzled so linear LDS dest ends up swizzled)
    const int ksw = (((lane & 3) ^ ((lane >> 3) & 3)) << 3);
    // read-side xor (row mod 16 via l16)
    const int rchunk = ((q ^ ((l16 >> 1) & 3)) << 3);

    f32x4 acc[4][4];
#pragma unroll
    for (int mt = 0; mt < 4; ++mt)
#pragma unroll
        for (int nt = 0; nt < 4; ++nt)
            acc[mt][nt] = (f32x4){0.f, 0.f, 0.f, 0.f};

    const bool useAl = (Apl != nullptr) || (Aph == nullptr);
    const int nkT = Kpad >> 5;
    const int Z = gridDim.z, zb = blockIdx.z;
    const int t0 = (nkT * zb) / Z, t1 = (nkT * (zb + 1)) / Z;

    auto stage = [&](int t) {
        const int k0 = t << 5;
#pragma unroll
        for (int i = 0; i < 2; ++i) {
            const int mb = (wave << 5) + (i << 4);
            const long gb = (long)(col0 + mb + l2) * Kpad + k0 + ksw;
            GL16(&Wth[gb], &Bh[mb * 32]);
            GL16(&Wtl[gb], &Bl[mb * 32]);
        }
        if (Aph) {
#pragma unroll
            for (int i = 0; i < 2; ++i) {
                const int mb = (wave << 5) + (i << 4);
                const long ga = (long)(row0 + mb + l2) * Kpad + k0 + ksw;
                GL16(&Aph[ga], &Ah[mb * 32]);
                if (Apl) GL16(&Apl[ga], &Al[mb * 32]);
            }
        } else {
#pragma unroll
            for (int s = 0; s < 4; ++s) {
                const int l  = (s << 8) + tid;
                const int m  = l >> 3;
                const int k4 = (l & 7) << 2;
                const float4 v = *(const float4*)&Afp[(long)(row0 + m) * Kpad + k0 + k4];
                const unsigned u0 = __float_as_uint(v.x), u1 = __float_as_uint(v.y);
                const unsigned u2 = __float_as_uint(v.z), u3 = __float_as_uint(v.w);
                const unsigned r0 = __float_as_uint(v.x - __uint_as_float(u0 & 0xFFFF0000u));
                const unsigned r1 = __float_as_uint(v.y - __uint_as_float(u1 & 0xFFFF0000u));
                const unsigned r2 = __float_as_uint(v.z - __uint_as_float(u2 & 0xFFFF0000u));
                const unsigned r3 = __float_as_uint(v.w - __uint_as_float(u3 & 0xFFFF0000u));
                const int off = m * 32 + ((((k4 >> 3) ^ ((m >> 1) & 3)) << 3) | (k4 & 4));
                *(int2*)&Ah[off] = make_int2((int)pack_hi(u0, u1), (int)pack_hi(u2, u3));
                *(int2*)&Al[off] = make_int2((int)pack_hi(r0, r1), (int)pack_hi(r2, r3));
            }
        }
    };

    stage(t0);
    __syncthreads();

    for (int t = t0; t < t1; ++t) {
        bf16x8 ah[4], al[4], bh[4], bl[4];
#pragma unroll
        for (int i = 0; i < 4; ++i) {
            const int mrow = (wr << 6) + (i << 4) + l16;
            const int ncol = (wc << 6) + (i << 4) + l16;
            ah[i] = *(const bf16x8*)&Ah[mrow * 32 + rchunk];
            if (useAl) al[i] = *(const bf16x8*)&Al[mrow * 32 + rchunk];
            bh[i] = *(const bf16x8*)&Bh[ncol * 32 + rchunk];
            bl[i] = *(const bf16x8*)&Bl[ncol * 32 + rchunk];
        }
        __syncthreads();                  // all waves done reading tile t
        if (t + 1 < t1) stage(t + 1);     // overwrite same buffers (async)
#pragma unroll
        for (int nt = 0; nt < 4; ++nt)
#pragma unroll
            for (int mt = 0; mt < 4; ++mt) {
                acc[mt][nt] = __builtin_amdgcn_mfma_f32_16x16x32_bf16(ah[mt], bh[nt], acc[mt][nt], 0, 0, 0);
                acc[mt][nt] = __builtin_amdgcn_mfma_f32_16x16x32_bf16(ah[mt], bl[nt], acc[mt][nt], 0, 0, 0);
                if (useAl)
                    acc[mt][nt] = __builtin_amdgcn_mfma_f32_16x16x32_bf16(al[mt], bh[nt], acc[mt][nt], 0, 0, 0);
            }
        __syncthreads();                  // drain staging (vmcnt0/lgkm0)
    }

    if (Cf && Z > 1) {                    // K-split: raw partial slab store
        float* dst = Cf + (long)zb * partStride;
#pragma unroll
        for (int mt = 0; mt < 4; ++mt)
#pragma unroll
            for (int nt = 0; nt < 4; ++nt) {
                const int col = col0 + (wc << 6) + (nt << 4) + l16;
#pragma unroll
                for (int rg = 0; rg < 4; ++rg) {
                    const int row = row0 + (wr << 6) + (mt << 4) + (q << 2) + rg;
                    dst[(long)row * N + col] = acc[mt][nt][rg];
                }
            }
        return;
    }

    if (Cpool) {
#pragma unroll
        for (int mt = 0; mt < 4; ++mt)
#pragma unroll
            for (int nt = 0; nt < 4; ++nt) {
                const int col = col0 + (wc << 6) + (nt << 4) + l16;
                float m = fmaxf(fmaxf(acc[mt][nt][0], acc[mt][nt][1]),
                                fmaxf(acc[mt][nt][2], acc[mt][nt][3]));
                m = fmaxf(m, __shfl_xor(m, 16));
                m = fmaxf(m, __shfl_xor(m, 32));
                m += bias[col];
                if (relu) m = fmaxf(m, 0.f);
                if (q == 0)
                    Cpool[(long)((row0 >> 4) + (wr << 2) + mt) * 768 + col] = m;
            }
        return;
    }
#pragma unroll
    for (int mt = 0; mt < 4; ++mt)
#pragma unroll
        for (int nt = 0; nt < 4; ++nt) {
            const int col = col0 + (wc << 6) + (nt << 4) + l16;
            const float bs = bias[col];
#pragma unroll
            for (int rg = 0; rg < 4; ++rg) {
                const int row = row0 + (wr << 6) + (mt << 4) + (q << 2) + rg;
                float v = acc[mt][nt][rg] + bs;
                if (relu) v = fmaxf(v, 0.f);
                if (Cf) Cf[(long)row * N + col] = v;
                if (Cph || Cp768) {
                    short h, l; split1(v, h, l);
                    if (Cph) {
                        Cph[(long)row * KpadOut + col] = h;
                        Cpl[(long)row * KpadOut + col] = l;
                    }
                    if (Cp768) Cp768[(long)row * 768 + col] = h;
                }
            }
        }
    if (CoordC && Cph && colb == 0 && tid < 128) {
        const int r = row0 + tid;
        const long rb = (long)r * KpadOut;
        const long cb = (long)(cfBase + r) * 5;
#pragma unroll
        for (int d = 0; d < 4; ++d) {
            short h, l; split1(CoordC[cb + 1 + d], h, l);
            Cph[rb + 768 + d] = h;
            Cpl[rb + 768 + d] = l;
        }
        for (int c = 772; c < 800; ++c) { Cph[rb + c] = 0; Cpl[rb + c] = 0; }
    }
}

// ---------------------------------------------------------------------------
// LayerNorm over K-split partials: z = relu(sum_z Fp[z] + bias45), then LN.
// 8 rows/block (4 waves x 2 rows), grid ch/8.
// ---------------------------------------------------------------------------
__global__ __launch_bounds__(256) void ln_kernel(const float* __restrict__ Fp,
                                                 long pstride,
                                                 const float* __restrict__ g,
                                                 const float* __restrict__ b,
                                                 const float* __restrict__ badd,
                                                 short* __restrict__ hp,
                                                 short* __restrict__ lp)
{
    const int tid = threadIdx.x, wave = tid >> 6, lane = tid & 63;
    float gv[4], bv[4], av[4];
#pragma unroll
    for (int j = 0; j < 4; ++j) {
        gv[j] = g[lane * 4 + j]; bv[j] = b[lane * 4 + j]; av[j] = badd[lane * 4 + j];
    }
    for (int i = 0; i < 2; ++i) {
        const int r = (blockIdx.x << 3) + (wave << 1) + i;
        const long off = (long)r * 256 + lane * 4;
        float4 x = *(const float4*)&Fp[off];
#pragma unroll
        for (int z = 1; z < ZSPLIT; ++z) {
            const float4 p = *(const float4*)&Fp[(long)z * pstride + off];
            x.x += p.x; x.y += p.y; x.z += p.z; x.w += p.w;
        }
        x.x = fmaxf(x.x + av[0], 0.f);
        x.y = fmaxf(x.y + av[1], 0.f);
        x.z = fmaxf(x.z + av[2], 0.f);
        x.w = fmaxf(x.w + av[3], 0.f);
        float s = x.x + x.y + x.z + x.w;
#pragma unroll
        for (int off2 = 32; off2; off2 >>= 1) s += __shfl_down(s, off2);
        const float mu = __shfl(s, 0) * (1.f / 256.f);
        const float d0 = x.x - mu, d1 = x.y - mu, d2 = x.z - mu, d3 = x.w - mu;
        float s2 = d0 * d0 + d1 * d1 + d2 * d2 + d3 * d3;
#pragma unroll
        for (int off2 = 32; off2; off2 >>= 1) s2 += __shfl_down(s2, off2);
        const float den = sqrtf(__shfl(s2, 0) * (1.f / 256.f) + 1e-5f);
        const float v[4] = { d0 / den * gv[0] + bv[0], d1 / den * gv[1] + bv[1],
                             d2 / den * gv[2] + bv[2], d3 / den * gv[3] + bv[3] };
#pragma unroll
        for (int j = 0; j < 4; ++j) {
            short h, l; split1(v[j], h, l);
            hp[(long)r * 256 + lane * 4 + j] = h;
            lp[(long)r * 256 + lane * 4 + j] = l;
        }
    }
}

// ---------------------------------------------------------------------------
// imp over K-split partials: z2 = relu(sum_z Fp[z] + ib2), then iw3 dot.
// 8 rows/block, grid ch/8.
// ---------------------------------------------------------------------------
__global__ __launch_bounds__(256) void imp_kernel(const float* __restrict__ Fp,
                                                  long pstride,
                                                  const float* __restrict__ iw3,
                                                  const float* __restrict__ ib3,
                                                  const float* __restrict__ ib2,
                                                  const float* __restrict__ noise,
                                                  const float* __restrict__ lt,
                                                  float* __restrict__ pert,
                                                  int base)
{
    const int tid = threadIdx.x, wave = tid >> 6, lane = tid & 63;
    float wv[4], bv[4];
#pragma unroll
    for (int j = 0; j < 4; ++j) { wv[j] = iw3[lane * 4 + j]; bv[j] = ib2[lane * 4 + j]; }
    const float temp = fmaxf(expf(lt[0]), 0.1f);
    const float b3v = ib3[0];
    for (int i = 0; i < 2; ++i) {
        const int r = (blockIdx.x << 3) + (wave << 1) + i;
        const long off = (long)r * 256 + lane * 4;
        float4 x = *(const float4*)&Fp[off];
#pragma unroll
        for (int z = 1; z < ZSPLIT; ++z) {
            const float4 p = *(const float4*)&Fp[(long)z * pstride + off];
            x.x += p.x; x.y += p.y; x.z += p.z; x.w += p.w;
        }
        float s = fmaxf(x.x + bv[0], 0.f) * wv[0] + fmaxf(x.y + bv[1], 0.f) * wv[1]
                + fmaxf(x.z + bv[2], 0.f) * wv[2] + fmaxf(x.w + bv[3], 0.f) * wv[3];
#pragma unroll
        for (int off2 = 32; off2; off2 >>= 1) s += __shfl_down(s, off2);
        if (lane == 0)
            pert[base + r] = (s + b3v + noise[base + r]) / temp;
    }
}

// ---------------------------------------------------------------------------
// top-128, two-phase (exact):
//  phase 1 (topk_part): 64 blocks = 8 events x 8 slices of 2048 points.
//    v3: TWO-LEVEL (16-bit) radix select. Round 12's single 8-bit level
//    failed: float MSB bytes take ~4-8 distinct values, so the threshold
//    bucket held hundreds of elems -> serial fallback -> 2.1ms. After 16
//    bits the tie bucket is ~1-4 elems (continuous data). Values live in
//    registers (8/thread) across both passes. Output set identical to the
//    verified single-block radix (total order fmap(v)<<32 | ~idx).
//  phase 2 (topk_merge): 8 blocks; bitonic-sort the 1024 candidates.
// ---------------------------------------------------------------------------
__device__ __forceinline__ unsigned fmap(float f) {
    unsigned x = __float_as_uint(f);
    return (x & 0x80000000u) ? ~x : (x | 0x80000000u);
}

__global__ __launch_bounds__(256) void topk_part(const float* __restrict__ pert,
                                                 unsigned long long* __restrict__ cand)
{
    const int e = blockIdx.x >> 3, s = blockIdx.x & 7, tid = threadIdx.x;
    const int base = e * PPE + s * 2048;
    const int c4 = tid & 3;
    __shared__ unsigned hist4[1024];             // x4-replicated 256-bin hist
    __shared__ unsigned long long gt[MT];
    __shared__ unsigned long long eqk[256];
    __shared__ int cgt, ceq, sh_need, sh_g1;
    __shared__ unsigned sh_b1, sh_b2;
    unsigned u[8];
#pragma unroll
    for (int i = 0; i < 8; ++i)
        u[i] = fmap(pert[base + (i << 8) + tid]);
    for (int i = tid; i < 1024; i += 256) hist4[i] = 0;
    if (tid == 0) { cgt = 0; ceq = 0; }
    __syncthreads();
    // ---- pass 1: histogram bits 31-24
#pragma unroll
    for (int i = 0; i < 8; ++i)
        atomicAdd(&hist4[((u[i] >> 24) << 2) | c4], 1u);
    __syncthreads();
    if (tid == 0) {
        int cum = 0, b = 255, cb = 0;
        for (; b > 0; --b) {
            cb = (int)(hist4[b << 2] + hist4[(b << 2) | 1]
                     + hist4[(b << 2) | 2] + hist4[(b << 2) | 3]);
            cum += cb;
            if (cum >= MT) break;
        }
        if (cum < MT) {
            cb = (int)(hist4[0] + hist4[1] + hist4[2] + hist4[3]);
            cum += cb; b = 0;
        }
        sh_b1 = (unsigned)b;
        sh_g1 = cum - cb;                 // #elems with top8 > b1 (< 128)
    }
    __syncthreads();
    const unsigned b1 = sh_b1;
    const int g1 = sh_g1;
    // ---- pass 2: histogram bits 23-16 within bucket b1
    for (int i = tid; i < 1024; i += 256) hist4[i] = 0;
    __syncthreads();
#pragma unroll
    for (int i = 0; i < 8; ++i)
        if ((u[i] >> 24) == b1)
            atomicAdd(&hist4[(((u[i] >> 16) & 255u) << 2) | c4], 1u);
    __syncthreads();
    if (tid == 0) {
        int cum = g1, b = 255, cb = 0;
        for (; b > 0; --b) {
            cb = (int)(hist4[b << 2] + hist4[(b << 2) | 1]
                     + hist4[(b << 2) | 2] + hist4[(b << 2) | 3]);
            cum += cb;
            if (cum >= MT) break;
        }
        if (cum < MT) {
            cb = (int)(hist4[0] + hist4[1] + hist4[2] + hist4[3]);
            cum += cb; b = 0;
        }
        sh_b2 = (unsigned)b;
        sh_need = MT - (cum - cb);        // take this many from tie bucket
    }
    __syncthreads();
    const unsigned b2 = sh_b2;
    const int need = sh_need;
    // ---- collect: strictly-greater (prefix16 > (b1,b2)) + tie bucket
#pragma unroll
    for (int i = 0; i < 8; ++i) {
        const unsigned t8 = u[i] >> 24;
        const unsigned m8 = (u[i] >> 16) & 255u;
        const int idx = base + (i << 8) + tid;
        const unsigned long long kk =
            ((unsigned long long)u[i] << 32) | (unsigned)(~idx);
        if (t8 > b1 || (t8 == b1 && m8 > b2)) {
            int qq = atomicAdd(&cgt, 1); if (qq < MT) gt[qq] = kk;
        } else if (t8 == b1 && m8 == b2) {
            int qq = atomicAdd(&ceq, 1); if (qq < 256) eqk[qq] = kk;
        }
    }
    __syncthreads();
    const int ngt = (cgt < MT) ? cgt : MT;        // by construction cgt < MT
    if (ceq <= 256) {
        if (tid >= ceq) eqk[tid] = 0ull;
        __syncthreads();
        for (int k = 2; k <= 256; k <<= 1)
            for (int j = k >> 1; j > 0; j >>= 1) {
                const int l = tid ^ j;
                if (l > tid) {
                    const unsigned long long a = eqk[tid], b = eqk[l];
                    const bool up = ((tid & k) == 0);
                    if (up ? (a < b) : (a > b)) { eqk[tid] = b; eqk[l] = a; }
                }
                __syncthreads();
            }
    } else {
        if (tid == 0) {                           // rare: >256 exact 16-bit ties
            unsigned long long sel[MT];
            int n = 0;
            for (int p = 0; p < 2048; ++p) {
                const unsigned uu = fmap(pert[base + p]);
                if ((uu >> 24) != b1 || ((uu >> 16) & 255u) != b2) continue;
                const unsigned long long kk =
                    ((unsigned long long)uu << 32) | (unsigned)(~(base + p));
                if (n < need) {
                    int j = n++;
                    while (j > 0 && sel[j - 1] < kk) { sel[j] = sel[j - 1]; --j; }
                    sel[j] = kk;
                } else if (kk > sel[need - 1]) {
                    int j = need - 1;
                    while (j > 0 && sel[j - 1] < kk) { sel[j] = sel[j - 1]; --j; }
                    sel[j] = kk;
                }
            }
            for (int j = 0; j < need; ++j) eqk[j] = sel[j];
        }
        __syncthreads();
    }
    if (tid < MT)
        cand[(long)blockIdx.x * MT + tid] = (tid < ngt) ? gt[tid] : eqk[tid - ngt];
}

__global__ __launch_bounds__(256) void topk_merge(const unsigned long long* __restrict__ cand,
                                                  const float4* __restrict__ c4f,
                                                  float* __restrict__ centf)
{
    const int e = blockIdx.x, tid = threadIdx.x;
    __shared__ unsigned long long key[1024];     // 8 KB
    for (int i = tid; i < 1024; i += 256)
        key[i] = cand[(long)e * 1024 + i];
    __syncthreads();
    for (int k = 2; k <= 1024; k <<= 1)
        for (int j = k >> 1; j > 0; j >>= 1) {
            for (int i = tid; i < 1024; i += 256) {
                const int l = i ^ j;
                if (l > i) {
                    const unsigned long long a = key[i], b = key[l];
                    const bool up = ((i & k) == 0);
                    if (up ? (a < b) : (a > b)) { key[i] = b; key[l] = a; }
                }
            }
            __syncthreads();
        }
    if (tid < MT) {
        const int idx = (int)(~(unsigned)(key[tid] & 0xFFFFFFFFu));
        *(float4*)&centf[(long)(e * MT + tid) * 4] = c4f[idx];
    }
}

// ---------------------------------------------------------------------------
// 16-NN per (event,centroid): 2-level cached radix, x4-replicated histograms
// ---------------------------------------------------------------------------
__device__ __forceinline__ unsigned d2bits(const float4 x, float c0, float c1,
                                           float c2, float c3) {
    const float q0 = __fmul_rn(c0 - x.x, c0 - x.x);
    const float q1 = __fmul_rn(c1 - x.y, c1 - x.y);
    const float q2 = __fmul_rn(c2 - x.z, c2 - x.z);
    const float q3 = __fmul_rn(c3 - x.w, c3 - x.w);
    return __float_as_uint(__fadd_rn(__fadd_rn(__fadd_rn(q0, q1), q2), q3));
}

__global__ __launch_bounds__(256) void knn_kernel(const float4* __restrict__ c4f,
                                                  const float* __restrict__ centf,
                                                  int* __restrict__ knn_idx)
{
    const int blk = blockIdx.x, tid = threadIdx.x;
    const int e = blk >> 7, base = e * PPE;
    const int c4 = tid & 3;
    const float c0 = centf[(long)blk * 4 + 0];
    const float c1 = centf[(long)blk * 4 + 1];
    const float c2 = centf[(long)blk * 4 + 2];
    const float c3 = centf[(long)blk * 4 + 3];
    __shared__ unsigned short d16[PPE];          // 32 KB
    __shared__ unsigned long long ubuf[664];
    __shared__ int sh_need; __shared__ unsigned sh_b;
    __shared__ int clt, ceq;
    unsigned* hist4 = (unsigned*)ubuf;           // 1024
    unsigned* histm = hist4 + 1024;              // 256
    for (int i = tid; i < 1024; i += 256) hist4[i] = 0;
    __syncthreads();
    for (int p = tid; p < PPE; p += 256) {
        const unsigned u = d2bits(c4f[base + p], c0, c1, c2, c3);
        d16[p] = (unsigned short)(u >> 16);
        atomicAdd(&hist4[((u >> 24) << 2) | c4], 1u);
    }
    __syncthreads();
    histm[tid] = hist4[tid << 2] + hist4[(tid << 2) | 1]
               + hist4[(tid << 2) | 2] + hist4[(tid << 2) | 3];
    __syncthreads();
    if (tid == 0) {
        int cum = 0, b = 0;
        for (; b < 255; ++b) { cum += (int)histm[b]; if (cum >= KNN) break; }
        if (cum < KNN) { cum += (int)histm[255]; b = 255; }
        sh_need = KNN - (cum - (int)histm[b]); sh_b = (unsigned)b;
    }
    __syncthreads();
    int need = sh_need;
    const unsigned b1v = sh_b;
    __syncthreads();
    for (int i = tid; i < 1024; i += 256) hist4[i] = 0;
    __syncthreads();
    for (int p = tid; p < PPE; p += 256) {
        const unsigned h = d16[p];
        if ((h >> 8) == b1v) atomicAdd(&hist4[((h & 255u) << 2) | c4], 1u);
    }
    __syncthreads();
    histm[tid] = hist4[tid << 2] + hist4[(tid << 2) | 1]
               + hist4[(tid << 2) | 2] + hist4[(tid << 2) | 3];
    __syncthreads();
    if (tid == 0) {
        int cum = 0, b = 0;
        for (; b < 255; ++b) { cum += (int)histm[b]; if (cum >= need) break; }
        if (cum < need) { cum += (int)histm[255]; b = 255; }
        sh_need = need - (cum - (int)histm[b]); sh_b = (unsigned)b;
    }
    __syncthreads();
    need = sh_need;
    const unsigned prefix16 = (b1v << 8) | sh_b;
    // ---- collect phase: re-carve ubuf
    int* lt_i = (int*)ubuf;                                   // 16
    unsigned* lt_u = (unsigned*)(lt_i + KNN);                 // 16
    int* eqbuf = (int*)(lt_u + KNN);                          // 256
    unsigned long long* key256 = (unsigned long long*)(eqbuf + 256);  // 256
    if (tid == 0) { clt = 0; ceq = 0; }
    __syncthreads();
    for (int p = tid; p < PPE; p += 256) {
        const unsigned h = d16[p];
        if (h < prefix16)        { int q = atomicAdd(&clt, 1); if (q < KNN) lt_i[q] = p; }
        else if (h == prefix16)  { int q = atomicAdd(&ceq, 1); if (q < 256) eqbuf[q] = p; }
    }
    __syncthreads();
    const int nlt = (clt < KNN) ? clt : KNN;
    if (tid < nlt) lt_u[tid] = d2bits(c4f[base + lt_i[tid]], c0, c1, c2, c3);
    if (ceq <= 256) {
        key256[tid] = (tid < ceq)
            ? (((unsigned long long)d2bits(c4f[base + eqbuf[tid]], c0, c1, c2, c3) << 32)
               | (unsigned)eqbuf[tid])
            : 0xFFFFFFFFFFFFFFFFull;
        __syncthreads();
        for (int k = 2; k <= 256; k <<= 1)
            for (int j = k >> 1; j > 0; j >>= 1) {
                const int l = tid ^ j;
                if (l > tid) {
                    const unsigned long long a = key256[tid], b = key256[l];
                    const bool up = ((tid & k) == 0);
                    if (up ? (a > b) : (a < b)) { key256[tid] = b; key256[l] = a; }
                }
                __syncthreads();
            }
    } else if (tid == 0) {
        unsigned long long sel[KNN];
        int n = 0;
        for (int p = 0; p < PPE; ++p) {
            if (d16[p] != (unsigned short)prefix16) continue;
            const unsigned long long kk =
                ((unsigned long long)d2bits(c4f[base + p], c0, c1, c2, c3) << 32) | (unsigned)p;
            if (n < need) {
                int j = n++;
                while (j > 0 && sel[j - 1] > kk) { sel[j] = sel[j - 1]; --j; }
                sel[j] = kk;
            } else if (kk < sel[need - 1]) {
                int j = need - 1;
                while (j > 0 && sel[j - 1] > kk) { sel[j] = sel[j - 1]; --j; }
                sel[j] = kk;
            }
        }
        for (int j = 0; j < need; ++j) key256[j] = sel[j];
    }
    __syncthreads();
    if (tid == 0) {
        unsigned long long fin[KNN];
        int n = 0;
        for (int i = 0; i < nlt; ++i) {
            const unsigned long long kk = ((unsigned long long)lt_u[i] << 32) | (unsigned)lt_i[i];
            int j = n++;
            while (j > 0 && fin[j - 1] > kk) { fin[j] = fin[j - 1]; --j; }
            fin[j] = kk;
        }
        for (int i = 0; i < need; ++i) {
            const unsigned long long kk = key256[i];
            int j = n++;
            while (j > 0 && fin[j - 1] > kk) { fin[j] = fin[j - 1]; --j; }
            fin[j] = kk;
        }
        for (int r = 0; r < KNN; ++r)
            knn_idx[blk * KNN + r] = base + (int)(unsigned)(fin[r] & 0xFFFFFFFFu);
    }
}

// ---------------------------------------------------------------------------
// emit parallel: grid (BATCH, 16)
// ---------------------------------------------------------------------------
__global__ __launch_bounds__(256) void emit_kernel(const float* __restrict__ centf,
                                                   const float* __restrict__ tokf,
                                                   float* __restrict__ out,
                                                   long out_size)
{
    const int e = blockIdx.x, s = blockIdx.y, tid = threadIdx.x;
    __shared__ float tv[MT];
    __shared__ int   rk[MT];
    if (tid < MT) tv[tid] = centf[(long)(e * MT + tid) * 4 + 3];
    __syncthreads();
    if (tid < MT) {
        const float t = tv[tid]; int r = 0;
        for (int j = 0; j < MT; ++j)
            r += (tv[j] < t || (tv[j] == t && j < tid)) ? 1 : 0;
        rk[tid] = r;
    }
    __syncthreads();
    const long cent_off = (long)BATCH * MT * TOKD;
    const long mask_off = cent_off + (long)BATCH * MT * 4;
    for (int i = s * 8; i < s * 8 + 8; ++i) {
        const float* src = tokf + ((size_t)e * MT + i) * TOKD;
        const long dst = ((long)e * MT + rk[i]) * TOKD;
        for (int t4 = tid; t4 < TOKD / 4; t4 += 256) {
            const float4 v = ((const float4*)src)[t4];
            const long g = dst + (long)t4 * 4;
            if (g + 3 < out_size) {
                *(float4*)&out[g] = v;
            } else {
                if (g + 0 < out_size) out[g + 0] = v.x;
                if (g + 1 < out_size) out[g + 1] = v.y;
                if (g + 2 < out_size) out[g + 2] = v.z;
                if (g + 3 < out_size) out[g + 3] = v.w;
            }
        }
    }
    if (s == 0) {
        for (int idx = tid; idx < MT * 4; idx += 256) {
            const int i = idx >> 2, d = idx & 3;
            const long g = cent_off + ((long)e * MT + rk[i]) * 4 + d;
            if (g < out_size) out[g] = centf[((long)e * MT + i) * 4 + d];
        }
        for (int idx = tid; idx < MT; idx += 256) {
            const long g = mask_off + (long)e * MT + idx;
            if (g < out_size) out[g] = 1.0f;
        }
    }
}

// ---------------------------------------------------------------------------
extern "C" void kernel_launch(void* const* d_in, const int* in_sizes, int n_in,
                              void* d_out, int out_size, void* d_ws, size_t ws_size,
                              hipStream_t stream)
{
    const float* coords = (const float*)d_in[0];
    const float* feats  = (const float*)d_in[1];
    const float* lt     = (const float*)d_in[2];
    const float* w1  = (const float*)d_in[3];  const float* b1  = (const float*)d_in[4];
    const float* w2  = (const float*)d_in[5];  const float* b2  = (const float*)d_in[6];
    const float* w3  = (const float*)d_in[7];  const float* b3  = (const float*)d_in[8];
    const float* w4  = (const float*)d_in[9];  const float* b4  = (const float*)d_in[10];
    const float* iw1 = (const float*)d_in[11]; const float* ib1 = (const float*)d_in[12];
    const float* lng = (const float*)d_in[13]; const float* lnb = (const float*)d_in[14];
    const float* iw2 = (const float*)d_in[15]; const float* ib2 = (const float*)d_in[16];
    const float* iw3 = (const float*)d_in[17]; const float* ib3 = (const float*)d_in[18];
    const float* nw1 = (const float*)d_in[19]; const float* nb1 = (const float*)d_in[20];
    const float* nw2 = (const float*)d_in[21]; const float* nb2 = (const float*)d_in[22];
    const float* noise = (const float*)d_in[23];

    const int NBR = BATCH * MT * KNN;   // 16384
    const size_t FIXED_FL = (size_t)NPT + 4096 + 16384 + 16384 + (size_t)1024 * TOKD
                          + (size_t)NPT * 4 + 256 + 2 * (size_t)1024 * TOKD;
    const size_t s_w2 = 512 * 256,  s_w3 = 768 * 512,  s_w4 = 768 * 768;
    const size_t s_45 = 256 * 800,  s_i2 = 256 * 256;
    const size_t s_n1 = 768 * 768,  s_n2 = 768 * 768;
    const size_t WTOT = 2 * (s_w2 + s_w3 + s_w4 + s_45 + s_i2 + s_n1 + s_n2);
    const size_t BASE_BYTES = FIXED_FL * 4 + WTOT * 2;
    // per-row: PA pair (800 wide) + PB pair (512 wide) + Fp slabs (Z x 256 f32)
    const size_t PERROW = (800 * 2 + 512 * 2) * 2 + (size_t)ZSPLIT * 256 * 4;  // 7296
    int ch = 128;
    // Uncapped doubling (round-8 verified best: ch=65536 @ 1673us beat the
    // CHMAX=16384 L3-residency cap @ 1801us — HBM absorbs activation traffic
    // at 1.8 TB/s; launch count/grid size dominate).
    while (ch < NPT && BASE_BYTES + (size_t)(ch * 2) * PERROW <= ws_size) ch <<= 1;
    const size_t H3_BYTES = (size_t)NPT * 768 * 2;
    const bool persist = (BASE_BYTES + (size_t)ch * PERROW + H3_BYTES) <= ws_size;

    float*  pert   = (float*)d_ws;
    float*  centf  = pert + NPT;
    int*    knn    = (int*)(centf + 4096);
    unsigned long long* cand = (unsigned long long*)(knn + 16384);   // 8192 u64
    float*  pooled = (float*)(cand + 8192);
    float4* c4f    = (float4*)(pooled + (size_t)1024 * TOKD);
    float*  bias45 = (float*)(c4f + NPT);
    float*  T1     = bias45 + 256;                      // 1024*768
    float*  T2     = T1 + (size_t)1024 * TOKD;          // 1024*768
    short*  wsp    = (short*)(T2 + (size_t)1024 * TOKD);
    short* w2h = wsp;            short* w2l = w2h + s_w2;
    short* w3h = w2l + s_w2;     short* w3l = w3h + s_w3;
    short* w4h = w3l + s_w3;     short* w4l = w4h + s_w4;
    short* f45h = w4l + s_w4;    short* f45l = f45h + s_45;
    short* i2h = f45l + s_45;    short* i2l = i2h + s_i2;
    short* n1h = i2l + s_i2;     short* n1l = n1h + s_n1;
    short* n2h = n1l + s_n1;     short* n2l = n2h + s_n2;
    short* PAh = n2l + s_n2;     short* PAl = PAh + (size_t)ch * 800;
    short* PBh = PAl + (size_t)ch * 800;
    short* PBl = PBh + (size_t)ch * 512;
    float* Fp  = (float*)(PBl + (size_t)ch * 512);      // ZSPLIT x ch x 256 fp32
    short* H3  = (short*)(Fp + (size_t)ZSPLIT * ch * 256);  // NPT*768 bf16-hi (opt)
    const long pstride = (long)ch * 256;

    prep_kernel<<<dim3((NPT + 255) / 256), dim3(256), 0, stream>>>(coords, c4f);
    wsplit_all<<<dim3(3840), dim3(256), 0, stream>>>(
        w2, w3, w4, iw2, nw1, nw2,
        w2h, w2l, w3h, w3l, w4h, w4l, i2h, i2l, n1h, n1l, n2h, n2l);
    w45_kernel<<<dim3(801), dim3(256), 0, stream>>>(w4, iw1, b4, ib1, f45h, f45l, bias45);

    for (int ck = 0; ck < NPT / ch; ++ck) {
        const int base = ck * ch;
        l1_kernel<<<dim3(ch / 64), dim3(256), 0, stream>>>(feats, w1, b1, PAh, PAl, base, nullptr);
        gemm_mf<<<dim3(512 / 128, ch / 128), dim3(256), 0, stream>>>(
            PAh, PAl, nullptr, 256, w2h, w2l, b2, PBh, PBl, 512,
            nullptr, nullptr, nullptr, nullptr, 0, 512, 1, 0);
        gemm_mf<<<dim3(768 / 128, ch / 128), dim3(256), 0, stream>>>(
            PBh, PBl, nullptr, 512, w3h, w3l, b3, PAh, PAl, 800,
            nullptr, persist ? (H3 + (size_t)base * 768) : nullptr, nullptr,
            coords, base, 768, 1, 0);
        // K-split x ZSPLIT, non-atomic partial slabs into Fp
        gemm_mf<<<dim3(256 / 128, ch / 128, ZSPLIT), dim3(256), 0, stream>>>(
            PAh, PAl, nullptr, 800, f45h, f45l, nullptr, nullptr, nullptr, 0,
            Fp, nullptr, nullptr, nullptr, 0, 256, 0, pstride);
        ln_kernel<<<dim3(ch / 8), dim3(256), 0, stream>>>(
            Fp, pstride, lng, lnb, bias45, PBh, PBl);
        gemm_mf<<<dim3(256 / 128, ch / 128, ZSPLIT), dim3(256), 0, stream>>>(
            PBh, PBl, nullptr, 256, i2h, i2l, nullptr, nullptr, nullptr, 0,
            Fp, nullptr, nullptr, nullptr, 0, 256, 0, pstride);
        imp_kernel<<<dim3(ch / 8), dim3(256), 0, stream>>>(
            Fp, pstride, iw3, ib3, ib2, noise, lt, pert, base);
    }

    topk_part<<<dim3(BATCH * 8), dim3(256), 0, stream>>>(pert, cand);
    topk_merge<<<dim3(BATCH), dim3(256), 0, stream>>>(cand, c4f, centf);
    knn_kernel<<<dim3(BATCH * MT), dim3(256), 0, stream>>>(c4f, centf, knn);

    const int rcch = (ch < NBR) ? ch : NBR;
    for (int rc = 0; rc < NBR / rcch; ++rc) {
        if (persist) {
            gather_h3_kernel<<<dim3(rcch), dim3(256), 0, stream>>>(
                H3, knn, rc * rcch, PAh);
            gemm_mf<<<dim3(768 / 128, rcch / 128), dim3(256), 0, stream>>>(
                PAh, nullptr, nullptr, 768, w4h, w4l, b4, nullptr, nullptr, 0,
                nullptr, nullptr, pooled + (size_t)(rc * rcch / 16) * 768,
                nullptr, 0, 768, 0, 0);
        } else {
            l1_kernel<<<dim3(rcch / 64), dim3(256), 0, stream>>>(feats, w1, b1, PAh, PAl, 0, knn + (size_t)rc * rcch);
            gemm_mf<<<dim3(512 / 128, rcch / 128), dim3(256), 0, stream>>>(
                PAh, PAl, nullptr, 256, w2h, w2l, b2, PBh, PBl, 512,
                nullptr, nullptr, nullptr, nullptr, 0, 512, 1, 0);
            gemm_mf<<<dim3(768 / 128, rcch / 128), dim3(256), 0, stream>>>(
                PBh, PBl, nullptr, 512, w3h, w3l, b3, PAh, PAl, 768,
                nullptr, nullptr, nullptr, nullptr, 0, 768, 1, 0);
            gemm_mf<<<dim3(768 / 128, rcch / 128), dim3(256), 0, stream>>>(
                PAh, PAl, nullptr, 768, w4h, w4l, b4, nullptr, nullptr, 0,
                nullptr, nullptr, pooled + (size_t)(rc * rcch / 16) * 768,
                nullptr, 0, 768, 0, 0);
        }
    }

    // ---- token MLP (1024x768, fp32-A) + parallel emit ----
    gemm_mf<<<dim3(768 / 128, 1024 / 128), dim3(256), 0, stream>>>(
        nullptr, nullptr, pooled, 768, n1h, n1l, nb1, nullptr, nullptr, 0,
        T1, nullptr, nullptr, nullptr, 0, 768, 1, 0);
    gemm_mf<<<dim3(768 / 128, 1024 / 128), dim3(256), 0, stream>>>(
        nullptr, nullptr, T1, 768, n2h, n2l, nb2, nullptr, nullptr, 0,
        T2, nullptr, nullptr, nullptr, 0, 768, 0, 0);
    emit_kernel<<<dim3(BATCH, 16), dim3(256), 0, stream>>>(
        centf, T2, (float*)d_out, (long)out_size);
}

// Round 14
// 1498.497 us; speedup vs baseline: 2.4313x; 1.0962x over previous
//
#include <hip/hip_runtime.h>
#include <hip/hip_bf16.h>

// GumbelSoftmaxTokenizer: B=8, P=16384, FEAT=6, TOK=768, MT=128, K=16, IH=256
// All inputs float32; output buffer float32 (tokens, cents, masks concat).
#define NPT   131072      // B*P
#define BATCH 8
#define PPE   16384
#define MT    128
#define KNN   16
#define TOKD  768
#define ZSPLIT 1          // K-split no longer needed at ch=65536 (f45 grid is
                          // already 1024 blocks); ZSPLIT=2 only doubled Fp
                          // slab traffic (+536 MB/run).

typedef short bf16x8 __attribute__((ext_vector_type(8)));
typedef float f32x4  __attribute__((ext_vector_type(4)));

#define GL16(g, l) __builtin_amdgcn_global_load_lds(                         \
    (const __attribute__((address_space(1))) void*)(g),                      \
    (__attribute__((address_space(3))) void*)(l), 16, 0, 0)

__device__ __forceinline__ unsigned pack_hi(unsigned u0, unsigned u1) {
    return (u0 >> 16) | (u1 & 0xFFFF0000u);
}
__device__ __forceinline__ void split1(float x, short& h, short& l) {
    const unsigned u = __float_as_uint(x);
    h = (short)(u >> 16);
    const float r = x - __uint_as_float(u & 0xFFFF0000u);
    l = (short)(__float_as_uint(r) >> 16);
}

// ---------------------------------------------------------------------------
// prep: c4f[i] = coords[i,1:5] packed float4
// ---------------------------------------------------------------------------
__global__ __launch_bounds__(256) void prep_kernel(const float* __restrict__ coords,
                                                   float4* __restrict__ c4f)
{
    const int i = blockIdx.x * 256 + threadIdx.x;
    if (i < NPT) {
        const long b = (long)i * 5;
        c4f[i] = make_float4(coords[b + 1], coords[b + 2], coords[b + 3], coords[b + 4]);
    }
}

// ---------------------------------------------------------------------------
// All weight pre-converts in ONE launch (segments by blockIdx)
// ---------------------------------------------------------------------------
__global__ __launch_bounds__(256) void wsplit_all(
    const float* __restrict__ w2, const float* __restrict__ w3,
    const float* __restrict__ w4, const float* __restrict__ iw2,
    const float* __restrict__ nw1, const float* __restrict__ nw2,
    short* w2h, short* w2l, short* w3h, short* w3l,
    short* w4h, short* w4l, short* i2h, short* i2l,
    short* n1h, short* n1l, short* n2h, short* n2l)
{
    const int b = blockIdx.x;
    const float* W; int K, N, Kpad, n; short *hi, *lo;
    if (b < 512)       { W = w2;  K = 256; N = 512; Kpad = 256; hi = w2h; lo = w2l; n = b; }
    else if (b < 1280) { W = w3;  K = 512; N = 768; Kpad = 512; hi = w3h; lo = w3l; n = b - 512; }
    else if (b < 2048) { W = w4;  K = 768; N = 768; Kpad = 768; hi = w4h; lo = w4l; n = b - 1280; }
    else if (b < 2304) { W = iw2; K = 256; N = 256; Kpad = 256; hi = i2h; lo = i2l; n = b - 2048; }
    else if (b < 3072) { W = nw1; K = 768; N = 768; Kpad = 768; hi = n1h; lo = n1l; n = b - 2304; }
    else               { W = nw2; K = 768; N = 768; Kpad = 768; hi = n2h; lo = n2l; n = b - 3072; }
    for (int k = threadIdx.x; k < Kpad; k += 256) {
        short h = 0, l = 0;
        if (k < K) split1(W[(long)k * N + n], h, l);
        hi[(long)n * Kpad + k] = h;
        lo[(long)n * Kpad + k] = l;
    }
}

// ---------------------------------------------------------------------------
// W45 fusion, parallel form: 801 blocks.
// ---------------------------------------------------------------------------
__global__ __launch_bounds__(256) void w45_kernel(const float* __restrict__ w4,
                                                  const float* __restrict__ iw1,
                                                  const float* __restrict__ b4,
                                                  const float* __restrict__ ib1,
                                                  short* __restrict__ hi,
                                                  short* __restrict__ lo,
                                                  float* __restrict__ bias45)
{
    const int k = blockIdx.x, n = threadIdx.x;
    if (k < 768) {
        const float* wr = w4 + (long)k * 768;
        float v0 = 0.f, v1 = 0.f, v2 = 0.f, v3 = 0.f;
        for (int j = 0; j < 768; j += 4) {
            v0 += wr[j]     * iw1[(long)j * 256 + n];
            v1 += wr[j + 1] * iw1[(long)(j + 1) * 256 + n];
            v2 += wr[j + 2] * iw1[(long)(j + 2) * 256 + n];
            v3 += wr[j + 3] * iw1[(long)(j + 3) * 256 + n];
        }
        const float v = (v0 + v1) + (v2 + v3);
        short h, l; split1(v, h, l);
        hi[(long)n * 800 + k] = h;
        lo[(long)n * 800 + k] = l;
    } else if (k < 800) {
        const float v = (k < 772) ? iw1[(long)k * 256 + n] : 0.f;
        short h, l; split1(v, h, l);
        hi[(long)n * 800 + k] = h;
        lo[(long)n * 800 + k] = l;
    } else {
        float v0 = 0.f, v1 = 0.f, v2 = 0.f, v3 = 0.f;
        for (int j = 0; j < 768; j += 4) {
            v0 += b4[j]     * iw1[(long)j * 256 + n];
            v1 += b4[j + 1] * iw1[(long)(j + 1) * 256 + n];
            v2 += b4[j + 2] * iw1[(long)(j + 2) * 256 + n];
            v3 += b4[j + 3] * iw1[(long)(j + 3) * 256 + n];
        }
        bias45[n] = (v0 + v1) + (v2 + v3) + ib1[n];
    }
}

// ---------------------------------------------------------------------------
// L1 multi-row: 64 rows/block
// ---------------------------------------------------------------------------
__global__ __launch_bounds__(256) void l1_kernel(const float* __restrict__ f,
                                                 const float* __restrict__ w1,
                                                 const float* __restrict__ b1,
                                                 short* __restrict__ hp,
                                                 short* __restrict__ lp,
                                                 int base,
                                                 const int* __restrict__ gather)
{
    const int r0 = blockIdx.x << 6, tid = threadIdx.x;
    float wc[6];
#pragma unroll
    for (int k = 0; k < 6; ++k) wc[k] = w1[k * 256 + tid];
    const float bb = b1[tid];
    for (int i = 0; i < 64; ++i) {
        const int r = r0 + i;
        int row = gather ? gather[r] : (base + r);
        row = (row < 0) ? 0 : ((row >= NPT) ? (NPT - 1) : row);
        float acc = bb;
#pragma unroll
        for (int k = 0; k < 6; ++k) acc += f[(long)row * 6 + k] * wc[k];
        acc = fmaxf(acc, 0.f);
        short h, l; split1(acc, h, l);
        hp[(long)r * 256 + tid] = h;
        lp[(long)r * 256 + tid] = l;
    }
}

// ---------------------------------------------------------------------------
// gather_h3: G[i][0:768] = H3[knn[off+i]][0:768]
// ---------------------------------------------------------------------------
__global__ __launch_bounds__(256) void gather_h3_kernel(const short* __restrict__ H3,
                                                        const int* __restrict__ knn_idx,
                                                        int off,
                                                        short* __restrict__ G)
{
    const int i = blockIdx.x;
    const int row = knn_idx[off + i];
    const int4* src = (const int4*)(H3 + (long)row * 768);
    int4* dst = (int4*)(G + (long)i * 768);
    if (threadIdx.x < 96) dst[threadIdx.x] = src[threadIdx.x];
}

// ---------------------------------------------------------------------------
// Split-bf16 MFMA GEMM, 128x128 tile, 4 waves in 2x2 (wave = 64x64 sub-tile).
// K-SPLIT (non-atomic): when partStride != 0, block z of gridDim.z computes
// K-steps [nk*z/Z, nk*(z+1)/Z) and stores RAW fp32 partials (no bias/relu)
// to Cf + z*partStride with plain coalesced stores; consumer sums the slabs.
// (Token-MLP calls pass Cf with partStride=0 -> normal bias+relu path.)
// Phase order per K-step (T3-minimum): ds_read frags -> barrier ->
// stage(t+1) -> MFMA -> barrier (drain hides under compute).
// LDS XOR-swizzled (0 bank conflicts, verified r1-r2).
// launch_bounds(256,3): VERIFIED config (84 VGPR, no spill). (256,5) forces
// the 8-wave VGPR step (<=64) -> 48 VGPR -> acc[] spills to scratch
// (FETCH 590MB/WRITE 939MB per dispatch, 4x regression — round 10).
// ---------------------------------------------------------------------------
__global__ __launch_bounds__(256, 3) void gemm_mf(
    const short* __restrict__ Aph, const short* __restrict__ Apl,
    const float* __restrict__ Afp, int Kpad,
    const short* __restrict__ Wth, const short* __restrict__ Wtl,
    const float* __restrict__ bias,
    short* __restrict__ Cph, short* __restrict__ Cpl, int KpadOut,
    float* __restrict__ Cf, short* __restrict__ Cp768,
    float* __restrict__ Cpool,
    const float* __restrict__ CoordC, int cfBase,
    int N, int relu, long partStride)
{
    __shared__ short Ah[128 * 32];
    __shared__ short Al[128 * 32];
    __shared__ short Bh[128 * 32];
    __shared__ short Bl[128 * 32];
    const int tid = threadIdx.x;
    int rowb, colb;
    {
        const int ncol = gridDim.x, nrow = gridDim.y;
        if ((nrow & 7) == 0) {
            const int id  = blockIdx.y * ncol + blockIdx.x;
            const int sgs = ncol << 3;
            const int sg = id / sgs, wi = id % sgs;
            rowb = (sg << 3) + (wi & 7);
            colb = wi >> 3;
        } else { rowb = blockIdx.y; colb = blockIdx.x; }
    }
    const int row0 = rowb << 7, col0 = colb << 7;
    const int wave = tid >> 6, lane = tid & 63;
    const int wr = wave >> 1, wc = wave & 1;
    const int q = lane >> 4, l16 = lane & 15;
    const int l2 = lane >> 2;
    // staging source chunk (pre-swizzled so linear LDS dest ends up swizzled)
    const int ksw = (((lane & 3) ^ ((lane >> 3) & 3)) << 3);
    // read-side xor (row mod 16 via l16)
    const int rchunk = ((q ^ ((l16 >> 1) & 3)) << 3);

    f32x4 acc[4][4];
#pragma unroll
    for (int mt = 0; mt < 4; ++mt)
#pragma unroll
        for (int nt = 0; nt < 4; ++nt)
            acc[mt][nt] = (f32x4){0.f, 0.f, 0.f, 0.f};

    const bool useAl = (Apl != nullptr) || (Aph == nullptr);
    const int nkT = Kpad >> 5;
    const int Z = gridDim.z, zb = blockIdx.z;
    const int t0 = (nkT * zb) / Z, t1 = (nkT * (zb + 1)) / Z;

    auto stage = [&](int t) {
        const int k0 = t << 5;
#pragma unroll
        for (int i = 0; i < 2; ++i) {
            const int mb = (wave << 5) + (i << 4);
            const long gb = (long)(col0 + mb + l2) * Kpad + k0 + ksw;
            GL16(&Wth[gb], &Bh[mb * 32]);
            GL16(&Wtl[gb], &Bl[mb * 32]);
        }
        if (Aph) {
#pragma unroll
            for (int i = 0; i < 2; ++i) {
                const int mb = (wave << 5) + (i << 4);
                const long ga = (long)(row0 + mb + l2) * Kpad + k0 + ksw;
                GL16(&Aph[ga], &Ah[mb * 32]);
                if (Apl) GL16(&Apl[ga], &Al[mb * 32]);
            }
        } else {
#pragma unroll
            for (int s = 0; s < 4; ++s) {
                const int l  = (s << 8) + tid;
                const int m  = l >> 3;
                const int k4 = (l & 7) << 2;
                const float4 v = *(const float4*)&Afp[(long)(row0 + m) * Kpad + k0 + k4];
                const unsigned u0 = __float_as_uint(v.x), u1 = __float_as_uint(v.y);
                const unsigned u2 = __float_as_uint(v.z), u3 = __float_as_uint(v.w);
                const unsigned r0 = __float_as_uint(v.x - __uint_as_float(u0 & 0xFFFF0000u));
                const unsigned r1 = __float_as_uint(v.y - __uint_as_float(u1 & 0xFFFF0000u));
                const unsigned r2 = __float_as_uint(v.z - __uint_as_float(u2 & 0xFFFF0000u));
                const unsigned r3 = __float_as_uint(v.w - __uint_as_float(u3 & 0xFFFF0000u));
                const int off = m * 32 + ((((k4 >> 3) ^ ((m >> 1) & 3)) << 3) | (k4 & 4));
                *(int2*)&Ah[off] = make_int2((int)pack_hi(u0, u1), (int)pack_hi(u2, u3));
                *(int2*)&Al[off] = make_int2((int)pack_hi(r0, r1), (int)pack_hi(r2, r3));
            }
        }
    };

    stage(t0);
    __syncthreads();

    for (int t = t0; t < t1; ++t) {
        bf16x8 ah[4], al[4], bh[4], bl[4];
#pragma unroll
        for (int i = 0; i < 4; ++i) {
            const int mrow = (wr << 6) + (i << 4) + l16;
            const int ncol = (wc << 6) + (i << 4) + l16;
            ah[i] = *(const bf16x8*)&Ah[mrow * 32 + rchunk];
            if (useAl) al[i] = *(const bf16x8*)&Al[mrow * 32 + rchunk];
            bh[i] = *(const bf16x8*)&Bh[ncol * 32 + rchunk];
            bl[i] = *(const bf16x8*)&Bl[ncol * 32 + rchunk];
        }
        __syncthreads();                  // all waves done reading tile t
        if (t + 1 < t1) stage(t + 1);     // overwrite same buffers (async)
#pragma unroll
        for (int nt = 0; nt < 4; ++nt)
#pragma unroll
            for (int mt = 0; mt < 4; ++mt) {
                acc[mt][nt] = __builtin_amdgcn_mfma_f32_16x16x32_bf16(ah[mt], bh[nt], acc[mt][nt], 0, 0, 0);
                acc[mt][nt] = __builtin_amdgcn_mfma_f32_16x16x32_bf16(ah[mt], bl[nt], acc[mt][nt], 0, 0, 0);
                if (useAl)
                    acc[mt][nt] = __builtin_amdgcn_mfma_f32_16x16x32_bf16(al[mt], bh[nt], acc[mt][nt], 0, 0, 0);
            }
        __syncthreads();                  // drain staging (vmcnt0/lgkm0)
    }

    if (Cf && partStride) {               // K-split: raw partial slab store
        float* dst = Cf + (long)zb * partStride;
#pragma unroll
        for (int mt = 0; mt < 4; ++mt)
#pragma unroll
            for (int nt = 0; nt < 4; ++nt) {
                const int col = col0 + (wc << 6) + (nt << 4) + l16;
#pragma unroll
                for (int rg = 0; rg < 4; ++rg) {
                    const int row = row0 + (wr << 6) + (mt << 4) + (q << 2) + rg;
                    dst[(long)row * N + col] = acc[mt][nt][rg];
                }
            }
        return;
    }

    if (Cpool) {
#pragma unroll
        for (int mt = 0; mt < 4; ++mt)
#pragma unroll
            for (int nt = 0; nt < 4; ++nt) {
                const int col = col0 + (wc << 6) + (nt << 4) + l16;
                float m = fmaxf(fmaxf(acc[mt][nt][0], acc[mt][nt][1]),
                                fmaxf(acc[mt][nt][2], acc[mt][nt][3]));
                m = fmaxf(m, __shfl_xor(m, 16));
                m = fmaxf(m, __shfl_xor(m, 32));
                m += bias[col];
                if (relu) m = fmaxf(m, 0.f);
                if (q == 0)
                    Cpool[(long)((row0 >> 4) + (wr << 2) + mt) * 768 + col] = m;
            }
        return;
    }
#pragma unroll
    for (int mt = 0; mt < 4; ++mt)
#pragma unroll
        for (int nt = 0; nt < 4; ++nt) {
            const int col = col0 + (wc << 6) + (nt << 4) + l16;
            const float bs = bias[col];
#pragma unroll
            for (int rg = 0; rg < 4; ++rg) {
                const int row = row0 + (wr << 6) + (mt << 4) + (q << 2) + rg;
                float v = acc[mt][nt][rg] + bs;
                if (relu) v = fmaxf(v, 0.f);
                if (Cf) Cf[(long)row * N + col] = v;
                if (Cph || Cp768) {
                    short h, l; split1(v, h, l);
                    if (Cph) {
                        Cph[(long)row * KpadOut + col] = h;
                        Cpl[(long)row * KpadOut + col] = l;
                    }
                    if (Cp768) Cp768[(long)row * 768 + col] = h;
                }
            }
        }
    if (CoordC && Cph && colb == 0 && tid < 128) {
        const int r = row0 + tid;
        const long rb = (long)r * KpadOut;
        const long cb = (long)(cfBase + r) * 5;
#pragma unroll
        for (int d = 0; d < 4; ++d) {
            short h, l; split1(CoordC[cb + 1 + d], h, l);
            Cph[rb + 768 + d] = h;
            Cpl[rb + 768 + d] = l;
        }
        for (int c = 772; c < 800; ++c) { Cph[rb + c] = 0; Cpl[rb + c] = 0; }
    }
}

// ---------------------------------------------------------------------------
// LayerNorm over K-split partials: z = relu(sum_z Fp[z] + bias45), then LN.
// 8 rows/block (4 waves x 2 rows), grid ch/8.
// ---------------------------------------------------------------------------
__global__ __launch_bounds__(256) void ln_kernel(const float* __restrict__ Fp,
                                                 long pstride,
                                                 const float* __restrict__ g,
                                                 const float* __restrict__ b,
                                                 const float* __restrict__ badd,
                                                 short* __restrict__ hp,
                                                 short* __restrict__ lp)
{
    const int tid = threadIdx.x, wave = tid >> 6, lane = tid & 63;
    float gv[4], bv[4], av[4];
#pragma unroll
    for (int j = 0; j < 4; ++j) {
        gv[j] = g[lane * 4 + j]; bv[j] = b[lane * 4 + j]; av[j] = badd[lane * 4 + j];
    }
    for (int i = 0; i < 2; ++i) {
        const int r = (blockIdx.x << 3) + (wave << 1) + i;
        const long off = (long)r * 256 + lane * 4;
        float4 x = *(const float4*)&Fp[off];
#pragma unroll
        for (int z = 1; z < ZSPLIT; ++z) {
            const float4 p = *(const float4*)&Fp[(long)z * pstride + off];
            x.x += p.x; x.y += p.y; x.z += p.z; x.w += p.w;
        }
        x.x = fmaxf(x.x + av[0], 0.f);
        x.y = fmaxf(x.y + av[1], 0.f);
        x.z = fmaxf(x.z + av[2], 0.f);
        x.w = fmaxf(x.w + av[3], 0.f);
        float s = x.x + x.y + x.z + x.w;
#pragma unroll
        for (int off2 = 32; off2; off2 >>= 1) s += __shfl_down(s, off2);
        const float mu = __shfl(s, 0) * (1.f / 256.f);
        const float d0 = x.x - mu, d1 = x.y - mu, d2 = x.z - mu, d3 = x.w - mu;
        float s2 = d0 * d0 + d1 * d1 + d2 * d2 + d3 * d3;
#pragma unroll
        for (int off2 = 32; off2; off2 >>= 1) s2 += __shfl_down(s2, off2);
        const float den = sqrtf(__shfl(s2, 0) * (1.f / 256.f) + 1e-5f);
        const float v[4] = { d0 / den * gv[0] + bv[0], d1 / den * gv[1] + bv[1],
                             d2 / den * gv[2] + bv[2], d3 / den * gv[3] + bv[3] };
#pragma unroll
        for (int j = 0; j < 4; ++j) {
            short h, l; split1(v[j], h, l);
            hp[(long)r * 256 + lane * 4 + j] = h;
            lp[(long)r * 256 + lane * 4 + j] = l;
        }
    }
}

// ---------------------------------------------------------------------------
// imp over K-split partials: z2 = relu(sum_z Fp[z] + ib2), then iw3 dot.
// 8 rows/block, grid ch/8.
// ---------------------------------------------------------------------------
__global__ __launch_bounds__(256) void imp_kernel(const float* __restrict__ Fp,
                                                  long pstride,
                                                  const float* __restrict__ iw3,
                                                  const float* __restrict__ ib3,
                                                  const float* __restrict__ ib2,
                                                  const float* __restrict__ noise,
                                                  const float* __restrict__ lt,
                                                  float* __restrict__ pert,
                                                  int base)
{
    const int tid = threadIdx.x, wave = tid >> 6, lane = tid & 63;
    float wv[4], bv[4];
#pragma unroll
    for (int j = 0; j < 4; ++j) { wv[j] = iw3[lane * 4 + j]; bv[j] = ib2[lane * 4 + j]; }
    const float temp = fmaxf(expf(lt[0]), 0.1f);
    const float b3v = ib3[0];
    for (int i = 0; i < 2; ++i) {
        const int r = (blockIdx.x << 3) + (wave << 1) + i;
        const long off = (long)r * 256 + lane * 4;
        float4 x = *(const float4*)&Fp[off];
#pragma unroll
        for (int z = 1; z < ZSPLIT; ++z) {
            const float4 p = *(const float4*)&Fp[(long)z * pstride + off];
            x.x += p.x; x.y += p.y; x.z += p.z; x.w += p.w;
        }
        float s = fmaxf(x.x + bv[0], 0.f) * wv[0] + fmaxf(x.y + bv[1], 0.f) * wv[1]
                + fmaxf(x.z + bv[2], 0.f) * wv[2] + fmaxf(x.w + bv[3], 0.f) * wv[3];
#pragma unroll
        for (int off2 = 32; off2; off2 >>= 1) s += __shfl_down(s, off2);
        if (lane == 0)
            pert[base + r] = (s + b3v + noise[base + r]) / temp;
    }
}

// ---------------------------------------------------------------------------
// top-128, two-phase (exact):
//  phase 1 (topk_part): 64 blocks = 8 events x 8 slices of 2048 points.
//    TWO-LEVEL (16-bit) radix select; values live in registers (8/thread).
//    Output set identical to the verified single-block radix
//    (total order fmap(v)<<32 | ~idx).
//  phase 2 (topk_merge): 8 blocks; bitonic-sort the 1024 candidates.
// ---------------------------------------------------------------------------
__device__ __forceinline__ unsigned fmap(float f) {
    unsigned x = __float_as_uint(f);
    return (x & 0x80000000u) ? ~x : (x | 0x80000000u);
}

__global__ __launch_bounds__(256) void topk_part(const float* __restrict__ pert,
                                                 unsigned long long* __restrict__ cand)
{
    const int e = blockIdx.x >> 3, s = blockIdx.x & 7, tid = threadIdx.x;
    const int base = e * PPE + s * 2048;
    const int c4 = tid & 3;
    __shared__ unsigned hist4[1024];             // x4-replicated 256-bin hist
    __shared__ unsigned long long gt[MT];
    __shared__ unsigned long long eqk[256];
    __shared__ int cgt, ceq, sh_need, sh_g1;
    __shared__ unsigned sh_b1, sh_b2;
    unsigned u[8];
#pragma unroll
    for (int i = 0; i < 8; ++i)
        u[i] = fmap(pert[base + (i << 8) + tid]);
    for (int i = tid; i < 1024; i += 256) hist4[i] = 0;
    if (tid == 0) { cgt = 0; ceq = 0; }
    __syncthreads();
    // ---- pass 1: histogram bits 31-24
#pragma unroll
    for (int i = 0; i < 8; ++i)
        atomicAdd(&hist4[((u[i] >> 24) << 2) | c4], 1u);
    __syncthreads();
    if (tid == 0) {
        int cum = 0, b = 255, cb = 0;
        for (; b > 0; --b) {
            cb = (int)(hist4[b << 2] + hist4[(b << 2) | 1]
                     + hist4[(b << 2) | 2] + hist4[(b << 2) | 3]);
            cum += cb;
            if (cum >= MT) break;
        }
        if (cum < MT) {
            cb = (int)(hist4[0] + hist4[1] + hist4[2] + hist4[3]);
            cum += cb; b = 0;
        }
        sh_b1 = (unsigned)b;
        sh_g1 = cum - cb;                 // #elems with top8 > b1 (< 128)
    }
    __syncthreads();
    const unsigned b1 = sh_b1;
    const int g1 = sh_g1;
    // ---- pass 2: histogram bits 23-16 within bucket b1
    for (int i = tid; i < 1024; i += 256) hist4[i] = 0;
    __syncthreads();
#pragma unroll
    for (int i = 0; i < 8; ++i)
        if ((u[i] >> 24) == b1)
            atomicAdd(&hist4[(((u[i] >> 16) & 255u) << 2) | c4], 1u);
    __syncthreads();
    if (tid == 0) {
        int cum = g1, b = 255, cb = 0;
        for (; b > 0; --b) {
            cb = (int)(hist4[b << 2] + hist4[(b << 2) | 1]
                     + hist4[(b << 2) | 2] + hist4[(b << 2) | 3]);
            cum += cb;
            if (cum >= MT) break;
        }
        if (cum < MT) {
            cb = (int)(hist4[0] + hist4[1] + hist4[2] + hist4[3]);
            cum += cb; b = 0;
        }
        sh_b2 = (unsigned)b;
        sh_need = MT - (cum - cb);        // take this many from tie bucket
    }
    __syncthreads();
    const unsigned b2 = sh_b2;
    const int need = sh_need;
    // ---- collect: strictly-greater (prefix16 > (b1,b2)) + tie bucket
#pragma unroll
    for (int i = 0; i < 8; ++i) {
        const unsigned t8 = u[i] >> 24;
        const unsigned m8 = (u[i] >> 16) & 255u;
        const int idx = base + (i << 8) + tid;
        const unsigned long long kk =
            ((unsigned long long)u[i] << 32) | (unsigned)(~idx);
        if (t8 > b1 || (t8 == b1 && m8 > b2)) {
            int qq = atomicAdd(&cgt, 1); if (qq < MT) gt[qq] = kk;
        } else if (t8 == b1 && m8 == b2) {
            int qq = atomicAdd(&ceq, 1); if (qq < 256) eqk[qq] = kk;
        }
    }
    __syncthreads();
    const int ngt = (cgt < MT) ? cgt : MT;        // by construction cgt < MT
    if (ceq <= 256) {
        if (tid >= ceq) eqk[tid] = 0ull;
        __syncthreads();
        for (int k = 2; k <= 256; k <<= 1)
            for (int j = k >> 1; j > 0; j >>= 1) {
                const int l = tid ^ j;
                if (l > tid) {
                    const unsigned long long a = eqk[tid], b = eqk[l];
                    const bool up = ((tid & k) == 0);
                    if (up ? (a < b) : (a > b)) { eqk[tid] = b; eqk[l] = a; }
                }
                __syncthreads();
            }
    } else {
        if (tid == 0) {                           // rare: >256 exact 16-bit ties
            unsigned long long sel[MT];
            int n = 0;
            for (int p = 0; p < 2048; ++p) {
                const unsigned uu = fmap(pert[base + p]);
                if ((uu >> 24) != b1 || ((uu >> 16) & 255u) != b2) continue;
                const unsigned long long kk =
                    ((unsigned long long)uu << 32) | (unsigned)(~(base + p));
                if (n < need) {
                    int j = n++;
                    while (j > 0 && sel[j - 1] < kk) { sel[j] = sel[j - 1]; --j; }
                    sel[j] = kk;
                } else if (kk > sel[need - 1]) {
                    int j = need - 1;
                    while (j > 0 && sel[j - 1] < kk) { sel[j] = sel[j - 1]; --j; }
                    sel[j] = kk;
                }
            }
            for (int j = 0; j < need; ++j) eqk[j] = sel[j];
        }
        __syncthreads();
    }
    if (tid < MT)
        cand[(long)blockIdx.x * MT + tid] = (tid < ngt) ? gt[tid] : eqk[tid - ngt];
}

__global__ __launch_bounds__(256) void topk_merge(const unsigned long long* __restrict__ cand,
                                                  const float4* __restrict__ c4f,
                                                  float* __restrict__ centf)
{
    const int e = blockIdx.x, tid = threadIdx.x;
    __shared__ unsigned long long key[1024];     // 8 KB
    for (int i = tid; i < 1024; i += 256)
        key[i] = cand[(long)e * 1024 + i];
    __syncthreads();
    for (int k = 2; k <= 1024; k <<= 1)
        for (int j = k >> 1; j > 0; j >>= 1) {
            for (int i = tid; i < 1024; i += 256) {
                const int l = i ^ j;
                if (l > i) {
                    const unsigned long long a = key[i], b = key[l];
                    const bool up = ((i & k) == 0);
                    if (up ? (a < b) : (a > b)) { key[i] = b; key[l] = a; }
                }
            }
            __syncthreads();
        }
    if (tid < MT) {
        const int idx = (int)(~(unsigned)(key[tid] & 0xFFFFFFFFu));
        *(float4*)&centf[(long)(e * MT + tid) * 4] = c4f[idx];
    }
}

// ---------------------------------------------------------------------------
// 16-NN per (event,centroid): 2-level cached radix, x4-replicated histograms
// ---------------------------------------------------------------------------
__device__ __forceinline__ unsigned d2bits(const float4 x, float c0, float c1,
                                           float c2, float c3) {
    const float q0 = __fmul_rn(c0 - x.x, c0 - x.x);
    const float q1 = __fmul_rn(c1 - x.y, c1 - x.y);
    const float q2 = __fmul_rn(c2 - x.z, c2 - x.z);
    const float q3 = __fmul_rn(c3 - x.w, c3 - x.w);
    return __float_as_uint(__fadd_rn(__fadd_rn(__fadd_rn(q0, q1), q2), q3));
}

__global__ __launch_bounds__(256) void knn_kernel(const float4* __restrict__ c4f,
                                                  const float* __restrict__ centf,
                                                  int* __restrict__ knn_idx)
{
    const int blk = blockIdx.x, tid = threadIdx.x;
    const int e = blk >> 7, base = e * PPE;
    const int c4 = tid & 3;
    const float c0 = centf[(long)blk * 4 + 0];
    const float c1 = centf[(long)blk * 4 + 1];
    const float c2 = centf[(long)blk * 4 + 2];
    const float c3 = centf[(long)blk * 4 + 3];
    __shared__ unsigned short d16[PPE];          // 32 KB
    __shared__ unsigned long long ubuf[664];
    __shared__ int sh_need; __shared__ unsigned sh_b;
    __shared__ int clt, ceq;
    unsigned* hist4 = (unsigned*)ubuf;           // 1024
    unsigned* histm = hist4 + 1024;              // 256
    for (int i = tid; i < 1024; i += 256) hist4[i] = 0;
    __syncthreads();
    for (int p = tid; p < PPE; p += 256) {
        const unsigned u = d2bits(c4f[base + p], c0, c1, c2, c3);
        d16[p] = (unsigned short)(u >> 16);
        atomicAdd(&hist4[((u >> 24) << 2) | c4], 1u);
    }
    __syncthreads();
    histm[tid] = hist4[tid << 2] + hist4[(tid << 2) | 1]
               + hist4[(tid << 2) | 2] + hist4[(tid << 2) | 3];
    __syncthreads();
    if (tid == 0) {
        int cum = 0, b = 0;
        for (; b < 255; ++b) { cum += (int)histm[b]; if (cum >= KNN) break; }
        if (cum < KNN) { cum += (int)histm[255]; b = 255; }
        sh_need = KNN - (cum - (int)histm[b]); sh_b = (unsigned)b;
    }
    __syncthreads();
    int need = sh_need;
    const unsigned b1v = sh_b;
    __syncthreads();
    for (int i = tid; i < 1024; i += 256) hist4[i] = 0;
    __syncthreads();
    for (int p = tid; p < PPE; p += 256) {
        const unsigned h = d16[p];
        if ((h >> 8) == b1v) atomicAdd(&hist4[((h & 255u) << 2) | c4], 1u);
    }
    __syncthreads();
    histm[tid] = hist4[tid << 2] + hist4[(tid << 2) | 1]
               + hist4[(tid << 2) | 2] + hist4[(tid << 2) | 3];
    __syncthreads();
    if (tid == 0) {
        int cum = 0, b = 0;
        for (; b < 255; ++b) { cum += (int)histm[b]; if (cum >= need) break; }
        if (cum < need) { cum += (int)histm[255]; b = 255; }
        sh_need = need - (cum - (int)histm[b]); sh_b = (unsigned)b;
    }
    __syncthreads();
    need = sh_need;
    const unsigned prefix16 = (b1v << 8) | sh_b;
    // ---- collect phase: re-carve ubuf
    int* lt_i = (int*)ubuf;                                   // 16
    unsigned* lt_u = (unsigned*)(lt_i + KNN);                 // 16
    int* eqbuf = (int*)(lt_u + KNN);                          // 256
    unsigned long long* key256 = (unsigned long long*)(eqbuf + 256);  // 256
    if (tid == 0) { clt = 0; ceq = 0; }
    __syncthreads();
    for (int p = tid; p < PPE; p += 256) {
        const unsigned h = d16[p];
        if (h < prefix16)        { int q = atomicAdd(&clt, 1); if (q < KNN) lt_i[q] = p; }
        else if (h == prefix16)  { int q = atomicAdd(&ceq, 1); if (q < 256) eqbuf[q] = p; }
    }
    __syncthreads();
    const int nlt = (clt < KNN) ? clt : KNN;
    if (tid < nlt) lt_u[tid] = d2bits(c4f[base + lt_i[tid]], c0, c1, c2, c3);
    if (ceq <= 256) {
        key256[tid] = (tid < ceq)
            ? (((unsigned long long)d2bits(c4f[base + eqbuf[tid]], c0, c1, c2, c3) << 32)
               | (unsigned)eqbuf[tid])
            : 0xFFFFFFFFFFFFFFFFull;
        __syncthreads();
        for (int k = 2; k <= 256; k <<= 1)
            for (int j = k >> 1; j > 0; j >>= 1) {
                const int l = tid ^ j;
                if (l > tid) {
                    const unsigned long long a = key256[tid], b = key256[l];
                    const bool up = ((tid & k) == 0);
                    if (up ? (a > b) : (a < b)) { key256[tid] = b; key256[l] = a; }
                }
                __syncthreads();
            }
    } else if (tid == 0) {
        unsigned long long sel[KNN];
        int n = 0;
        for (int p = 0; p < PPE; ++p) {
            if (d16[p] != (unsigned short)prefix16) continue;
            const unsigned long long kk =
                ((unsigned long long)d2bits(c4f[base + p], c0, c1, c2, c3) << 32) | (unsigned)p;
            if (n < need) {
                int j = n++;
                while (j > 0 && sel[j - 1] > kk) { sel[j] = sel[j - 1]; --j; }
                sel[j] = kk;
            } else if (kk < sel[need - 1]) {
                int j = need - 1;
                while (j > 0 && sel[j - 1] > kk) { sel[j] = sel[j - 1]; --j; }
                sel[j] = kk;
            }
        }
        for (int j = 0; j < need; ++j) key256[j] = sel[j];
    }
    __syncthreads();
    if (tid == 0) {
        unsigned long long fin[KNN];
        int n = 0;
        for (int i = 0; i < nlt; ++i) {
            const unsigned long long kk = ((unsigned long long)lt_u[i] << 32) | (unsigned)lt_i[i];
            int j = n++;
            while (j > 0 && fin[j - 1] > kk) { fin[j] = fin[j - 1]; --j; }
            fin[j] = kk;
        }
        for (int i = 0; i < need; ++i) {
            const unsigned long long kk = key256[i];
            int j = n++;
            while (j > 0 && fin[j - 1] > kk) { fin[j] = fin[j - 1]; --j; }
            fin[j] = kk;
        }
        for (int r = 0; r < KNN; ++r)
            knn_idx[blk * KNN + r] = base + (int)(unsigned)(fin[r] & 0xFFFFFFFFu);
    }
}

// ---------------------------------------------------------------------------
// emit parallel: grid (BATCH, 16)
// ---------------------------------------------------------------------------
__global__ __launch_bounds__(256) void emit_kernel(const float* __restrict__ centf,
                                                   const float* __restrict__ tokf,
                                                   float* __restrict__ out,
                                                   long out_size)
{
    const int e = blockIdx.x, s = blockIdx.y, tid = threadIdx.x;
    __shared__ float tv[MT];
    __shared__ int   rk[MT];
    if (tid < MT) tv[tid] = centf[(long)(e * MT + tid) * 4 + 3];
    __syncthreads();
    if (tid < MT) {
        const float t = tv[tid]; int r = 0;
        for (int j = 0; j < MT; ++j)
            r += (tv[j] < t || (tv[j] == t && j < tid)) ? 1 : 0;
        rk[tid] = r;
    }
    __syncthreads();
    const long cent_off = (long)BATCH * MT * TOKD;
    const long mask_off = cent_off + (long)BATCH * MT * 4;
    for (int i = s * 8; i < s * 8 + 8; ++i) {
        const float* src = tokf + ((size_t)e * MT + i) * TOKD;
        const long dst = ((long)e * MT + rk[i]) * TOKD;
        for (int t4 = tid; t4 < TOKD / 4; t4 += 256) {
            const float4 v = ((const float4*)src)[t4];
            const long g = dst + (long)t4 * 4;
            if (g + 3 < out_size) {
                *(float4*)&out[g] = v;
            } else {
                if (g + 0 < out_size) out[g + 0] = v.x;
                if (g + 1 < out_size) out[g + 1] = v.y;
                if (g + 2 < out_size) out[g + 2] = v.z;
                if (g + 3 < out_size) out[g + 3] = v.w;
            }
        }
    }
    if (s == 0) {
        for (int idx = tid; idx < MT * 4; idx += 256) {
            const int i = idx >> 2, d = idx & 3;
            const long g = cent_off + ((long)e * MT + rk[i]) * 4 + d;
            if (g < out_size) out[g] = centf[((long)e * MT + i) * 4 + d];
        }
        for (int idx = tid; idx < MT; idx += 256) {
            const long g = mask_off + (long)e * MT + idx;
            if (g < out_size) out[g] = 1.0f;
        }
    }
}

// ---------------------------------------------------------------------------
extern "C" void kernel_launch(void* const* d_in, const int* in_sizes, int n_in,
                              void* d_out, int out_size, void* d_ws, size_t ws_size,
                              hipStream_t stream)
{
    const float* coords = (const float*)d_in[0];
    const float* feats  = (const float*)d_in[1];
    const float* lt     = (const float*)d_in[2];
    const float* w1  = (const float*)d_in[3];  const float* b1  = (const float*)d_in[4];
    const float* w2  = (const float*)d_in[5];  const float* b2  = (const float*)d_in[6];
    const float* w3  = (const float*)d_in[7];  const float* b3  = (const float*)d_in[8];
    const float* w4  = (const float*)d_in[9];  const float* b4  = (const float*)d_in[10];
    const float* iw1 = (const float*)d_in[11]; const float* ib1 = (const float*)d_in[12];
    const float* lng = (const float*)d_in[13]; const float* lnb = (const float*)d_in[14];
    const float* iw2 = (const float*)d_in[15]; const float* ib2 = (const float*)d_in[16];
    const float* iw3 = (const float*)d_in[17]; const float* ib3 = (const float*)d_in[18];
    const float* nw1 = (const float*)d_in[19]; const float* nb1 = (const float*)d_in[20];
    const float* nw2 = (const float*)d_in[21]; const float* nb2 = (const float*)d_in[22];
    const float* noise = (const float*)d_in[23];

    const int NBR = BATCH * MT * KNN;   // 16384
    const size_t FIXED_FL = (size_t)NPT + 4096 + 16384 + 16384 + (size_t)1024 * TOKD
                          + (size_t)NPT * 4 + 256 + 2 * (size_t)1024 * TOKD;
    const size_t s_w2 = 512 * 256,  s_w3 = 768 * 512,  s_w4 = 768 * 768;
    const size_t s_45 = 256 * 800,  s_i2 = 256 * 256;
    const size_t s_n1 = 768 * 768,  s_n2 = 768 * 768;
    const size_t WTOT = 2 * (s_w2 + s_w3 + s_w4 + s_45 + s_i2 + s_n1 + s_n2);
    const size_t BASE_BYTES = FIXED_FL * 4 + WTOT * 2;
    // per-row: PA pair (800 wide) + PB pair (512 wide) + Fp slab (Z x 256 f32)
    const size_t PERROW = (800 * 2 + 512 * 2) * 2 + (size_t)ZSPLIT * 256 * 4;  // 6272
    int ch = 128;
    // Cap at NPT/2 = 65536: the verified-best configuration (round 8/13).
    // (Uncapping to NPT could flip `persist` false at the unknown ws size.)
    while (ch < (NPT >> 1) && BASE_BYTES + (size_t)(ch * 2) * PERROW <= ws_size) ch <<= 1;
    const size_t H3_BYTES = (size_t)NPT * 768 * 2;
    const bool persist = (BASE_BYTES + (size_t)ch * PERROW + H3_BYTES) <= ws_size;

    float*  pert   = (float*)d_ws;
    float*  centf  = pert + NPT;
    int*    knn    = (int*)(centf + 4096);
    unsigned long long* cand = (unsigned long long*)(knn + 16384);   // 8192 u64
    float*  pooled = (float*)(cand + 8192);
    float4* c4f    = (float4*)(pooled + (size_t)1024 * TOKD);
    float*  bias45 = (float*)(c4f + NPT);
    float*  T1     = bias45 + 256;                      // 1024*768
    float*  T2     = T1 + (size_t)1024 * TOKD;          // 1024*768
    short*  wsp    = (short*)(T2 + (size_t)1024 * TOKD);
    short* w2h = wsp;            short* w2l = w2h + s_w2;
    short* w3h = w2l + s_w2;     short* w3l = w3h + s_w3;
    short* w4h = w3l + s_w3;     short* w4l = w4h + s_w4;
    short* f45h = w4l + s_w4;    short* f45l = f45h + s_45;
    short* i2h = f45l + s_45;    short* i2l = i2h + s_i2;
    short* n1h = i2l + s_i2;     short* n1l = n1h + s_n1;
    short* n2h = n1l + s_n1;     short* n2l = n2h + s_n2;
    short* PAh = n2l + s_n2;     short* PAl = PAh + (size_t)ch * 800;
    short* PBh = PAl + (size_t)ch * 800;
    short* PBl = PBh + (size_t)ch * 512;
    float* Fp  = (float*)(PBl + (size_t)ch * 512);      // ZSPLIT x ch x 256 fp32
    short* H3  = (short*)(Fp + (size_t)ZSPLIT * ch * 256);  // NPT*768 bf16-hi (opt)
    const long pstride = (long)ch * 256;

    prep_kernel<<<dim3((NPT + 255) / 256), dim3(256), 0, stream>>>(coords, c4f);
    wsplit_all<<<dim3(3840), dim3(256), 0, stream>>>(
        w2, w3, w4, iw2, nw1, nw2,
        w2h, w2l, w3h, w3l, w4h, w4l, i2h, i2l, n1h, n1l, n2h, n2l);
    w45_kernel<<<dim3(801), dim3(256), 0, stream>>>(w4, iw1, b4, ib1, f45h, f45l, bias45);

    for (int ck = 0; ck < NPT / ch; ++ck) {
        const int base = ck * ch;
        l1_kernel<<<dim3(ch / 64), dim3(256), 0, stream>>>(feats, w1, b1, PAh, PAl, base, nullptr);
        gemm_mf<<<dim3(512 / 128, ch / 128), dim3(256), 0, stream>>>(
            PAh, PAl, nullptr, 256, w2h, w2l, b2, PBh, PBl, 512,
            nullptr, nullptr, nullptr, nullptr, 0, 512, 1, 0);
        gemm_mf<<<dim3(768 / 128, ch / 128), dim3(256), 0, stream>>>(
            PBh, PBl, nullptr, 512, w3h, w3l, b3, PAh, PAl, 800,
            nullptr, persist ? (H3 + (size_t)base * 768) : nullptr, nullptr,
            coords, base, 768, 1, 0);
        // raw fp32 slab into Fp (partStride != 0 -> slab path; Z = ZSPLIT)
        gemm_mf<<<dim3(256 / 128, ch / 128, ZSPLIT), dim3(256), 0, stream>>>(
            PAh, PAl, nullptr, 800, f45h, f45l, nullptr, nullptr, nullptr, 0,
            Fp, nullptr, nullptr, nullptr, 0, 256, 0, pstride);
        ln_kernel<<<dim3(ch / 8), dim3(256), 0, stream>>>(
            Fp, pstride, lng, lnb, bias45, PBh, PBl);
        gemm_mf<<<dim3(256 / 128, ch / 128, ZSPLIT), dim3(256), 0, stream>>>(
            PBh, PBl, nullptr, 256, i2h, i2l, nullptr, nullptr, nullptr, 0,
            Fp, nullptr, nullptr, nullptr, 0, 256, 0, pstride);
        imp_kernel<<<dim3(ch / 8), dim3(256), 0, stream>>>(
            Fp, pstride, iw3, ib3, ib2, noise, lt, pert, base);
    }

    topk_part<<<dim3(BATCH * 8), dim3(256), 0, stream>>>(pert, cand);
    topk_merge<<<dim3(BATCH), dim3(256), 0, stream>>>(cand, c4f, centf);
    knn_kernel<<<dim3(BATCH * MT), dim3(256), 0, stream>>>(c4f, centf, knn);

    const int rcch = (ch < NBR) ? ch : NBR;
    for (int rc = 0; rc < NBR / rcch; ++rc) {
        if (persist) {
            gather_h3_kernel<<<dim3(rcch), dim3(256), 0, stream>>>(
                H3, knn, rc * rcch, PAh);
            gemm_mf<<<dim3(768 / 128, rcch / 128), dim3(256), 0, stream>>>(
                PAh, nullptr, nullptr, 768, w4h, w4l, b4, nullptr, nullptr, 0,
                nullptr, nullptr, pooled + (size_t)(rc * rcch / 16) * 768,
                nullptr, 0, 768, 0, 0);
        } else {
            l1_kernel<<<dim3(rcch / 64), dim3(256), 0, stream>>>(feats, w1, b1, PAh, PAl, 0, knn + (size_t)rc * rcch);
            gemm_mf<<<dim3(512 / 128, rcch / 128), dim3(256), 0, stream>>>(
                PAh, PAl, nullptr, 256, w2h, w2l, b2, PBh, PBl, 512,
                nullptr, nullptr, nullptr, nullptr, 0, 512, 1, 0);
            gemm_mf<<<dim3(768 / 128, rcch / 128), dim3(256), 0, stream>>>(
                PBh, PBl, nullptr, 512, w3h, w3l, b3, PAh, PAl, 768,
                nullptr, nullptr, nullptr, nullptr, 0, 768, 1, 0);
            gemm_mf<<<dim3(768 / 128, rcch / 128), dim3(256), 0, stream>>>(
                PAh, PAl, nullptr, 768, w4h, w4l, b4, nullptr, nullptr, 0,
                nullptr, nullptr, pooled + (size_t)(rc * rcch / 16) * 768,
                nullptr, 0, 768, 0, 0);
        }
    }

    // ---- token MLP (1024x768, fp32-A) + parallel emit ----
    gemm_mf<<<dim3(768 / 128, 1024 / 128), dim3(256), 0, stream>>>(
        nullptr, nullptr, pooled, 768, n1h, n1l, nb1, nullptr, nullptr, 0,
        T1, nullptr, nullptr, nullptr, 0, 768, 1, 0);
    gemm_mf<<<dim3(768 / 128, 1024 / 128), dim3(256), 0, stream>>>(
        nullptr, nullptr, T1, 768, n2h, n2l, nb2, nullptr, nullptr, 0,
        T2, nullptr, nullptr, nullptr, 0, 768, 0, 0);
    emit_kernel<<<dim3(BATCH, 16), dim3(256), 0, stream>>>(
        centf, T2, (float*)d_out, (long)out_size);
}